// Round 6
// baseline (25767.691 us; speedup 1.0000x reference)
//
#include <hip/hip_runtime.h>
#include <hip/hip_bf16.h>
#include <hip/hip_fp16.h>

// Problem constants (fixed by the reference)
#define FDIM 128      // F_IN == H == 128
#define G4H  512      // 4*H

typedef float f32x2 __attribute__((ext_vector_type(2)));

// ---------------------------------------------------------------------------
// degree / normalization
// ---------------------------------------------------------------------------
__global__ void deg_kernel(const int* __restrict__ ei, int* __restrict__ deg, int E) {
    int e = blockIdx.x * 256 + threadIdx.x;
    if (e < E) atomicAdd(&deg[ei[E + e]], 1);
}

__global__ void dinv_kernel(const int* __restrict__ deg, float* __restrict__ dinv, int N) {
    int n = blockIdx.x * 256 + threadIdx.x;
    if (n < N) dinv[n] = rsqrtf((float)(deg[n] + 1));   // +1 self-loop
}

// ---------------------------------------------------------------------------
// Pack w_hh [512 x 128] fp32 -> [512 x 64] packed half2 (K-pairs).
// ---------------------------------------------------------------------------
__global__ void pack_whh(const float* __restrict__ whh, float* __restrict__ whp, int n) {
    int i = blockIdx.x * 256 + threadIdx.x;   // n = 512*64
    if (i >= n) return;
    int row = i >> 6, p = i & 63;
    __half lo = __float2half(whh[row * FDIM + 2 * p]);
    __half hi = __float2half(whh[row * FDIM + 2 * p + 1]);
    unsigned u = ((unsigned)__half_as_ushort(hi) << 16) | (unsigned)__half_as_ushort(lo);
    whp[i] = __uint_as_float(u);
}

// ---------------------------------------------------------------------------
// C[M x 128] = A[M x 128] @ B[128 x 128]   (B is K-major: B[k*128 + j])
// ---------------------------------------------------------------------------
__global__ __launch_bounds__(256) void gemm_nn(const float* __restrict__ A,
                                               const float* __restrict__ B,
                                               float* __restrict__ C, int M) {
    __shared__ float Bl[64 * 132];
    __shared__ float Al[32][FDIM];
    const int tid = threadIdx.x;
    const int row0 = blockIdx.x * 32;

    for (int i = tid * 4; i < 32 * FDIM; i += 1024) {
        int r = i >> 7, k = i & 127;
        int row = row0 + r;
        float4 v = make_float4(0.f, 0.f, 0.f, 0.f);
        if (row < M) v = *(const float4*)(A + (size_t)row * FDIM + k);
        *(float4*)&Al[r][k] = v;
    }

    const int jg = tid & 31, rg = tid >> 5;
    float acc[4][4] = {};

    for (int kh = 0; kh < 2; ++kh) {
        __syncthreads();
        for (int i = tid * 4; i < 64 * FDIM; i += 1024) {
            int k = i >> 7, j = i & 127;
            *(float4*)&Bl[k * 132 + j] = *(const float4*)(B + (size_t)(kh * 64 + k) * FDIM + j);
        }
        __syncthreads();
        #pragma unroll 4
        for (int k = 0; k < 64; ++k) {
            float4 b4 = *(const float4*)&Bl[k * 132 + jg * 4];
            #pragma unroll
            for (int rr = 0; rr < 4; ++rr) {
                float a = Al[rg * 4 + rr][kh * 64 + k];
                acc[rr][0] += a * b4.x; acc[rr][1] += a * b4.y;
                acc[rr][2] += a * b4.z; acc[rr][3] += a * b4.w;
            }
        }
    }
    #pragma unroll
    for (int rr = 0; rr < 4; ++rr) {
        int row = row0 + rg * 4 + rr;
        if (row < M) {
            float4 v = make_float4(acc[rr][0], acc[rr][1], acc[rr][2], acc[rr][3]);
            *(float4*)(C + (size_t)row * FDIM + jg * 4) = v;
        }
    }
}

// ---------------------------------------------------------------------------
// xg[M x 512] = A[M x 128] @ B^T  (+ b_ih + b_hh), B is [512 x 128] row-major.
// ---------------------------------------------------------------------------
__global__ __launch_bounds__(256) void gemm_nt_xg(const float* __restrict__ A,
                                                  const float* __restrict__ B,
                                                  const float* __restrict__ bih,
                                                  const float* __restrict__ bhh,
                                                  float* __restrict__ C, int M) {
    __shared__ float Bl[64 * 132];
    __shared__ float Al[32][FDIM];
    const int tid = threadIdx.x;
    const int row0 = blockIdx.x * 32;
    const int chunk = blockIdx.y;

    for (int i = tid * 4; i < 32 * FDIM; i += 1024) {
        int r = i >> 7, k = i & 127;
        int row = row0 + r;
        float4 v = make_float4(0.f, 0.f, 0.f, 0.f);
        if (row < M) v = *(const float4*)(A + (size_t)row * FDIM + k);
        *(float4*)&Al[r][k] = v;
    }

    const int jg = tid & 31, rg = tid >> 5;
    float acc[4][4] = {};

    for (int kh = 0; kh < 2; ++kh) {
        __syncthreads();
        for (int i = tid * 4; i < 128 * 64; i += 1024) {
            int g = i >> 6, kl = i & 63;
            float4 v = *(const float4*)(B + (size_t)(chunk * 128 + g) * FDIM + kh * 64 + kl);
            Bl[(kl + 0) * 132 + g] = v.x;
            Bl[(kl + 1) * 132 + g] = v.y;
            Bl[(kl + 2) * 132 + g] = v.z;
            Bl[(kl + 3) * 132 + g] = v.w;
        }
        __syncthreads();
        #pragma unroll 4
        for (int k = 0; k < 64; ++k) {
            float4 b4 = *(const float4*)&Bl[k * 132 + jg * 4];
            #pragma unroll
            for (int rr = 0; rr < 4; ++rr) {
                float a = Al[rg * 4 + rr][kh * 64 + k];
                acc[rr][0] += a * b4.x; acc[rr][1] += a * b4.y;
                acc[rr][2] += a * b4.z; acc[rr][3] += a * b4.w;
            }
        }
    }
    const int col0 = chunk * 128 + jg * 4;
    float4 bsum = make_float4(bih[col0 + 0] + bhh[col0 + 0],
                              bih[col0 + 1] + bhh[col0 + 1],
                              bih[col0 + 2] + bhh[col0 + 2],
                              bih[col0 + 3] + bhh[col0 + 3]);
    #pragma unroll
    for (int rr = 0; rr < 4; ++rr) {
        int row = row0 + rg * 4 + rr;
        if (row < M) {
            float4 v = make_float4(acc[rr][0] + bsum.x, acc[rr][1] + bsum.y,
                                   acc[rr][2] + bsum.z, acc[rr][3] + bsum.w);
            *(float4*)(C + (size_t)row * G4H + col0) = v;
        }
    }
}

// ---------------------------------------------------------------------------
// GCN aggregation
// ---------------------------------------------------------------------------
__global__ void agg_init(const float* __restrict__ y, const float* __restrict__ dinv,
                         const float* __restrict__ bias, float* __restrict__ o, int N) {
    int idx = blockIdx.x * 256 + threadIdx.x;
    int n = idx >> 5, cc = (idx & 31) * 4;
    if (n >= N) return;
    float s = dinv[n]; s = s * s;
    float4 v = *(const float4*)(y + (size_t)n * FDIM + cc);
    float4 b = *(const float4*)(bias + cc);
    float4 r = make_float4(v.x * s + b.x, v.y * s + b.y, v.z * s + b.z, v.w * s + b.w);
    *(float4*)(o + (size_t)n * FDIM + cc) = r;
}

__global__ void agg_edges(const float* __restrict__ y, const int* __restrict__ ei,
                          const float* __restrict__ dinv, float* __restrict__ o, int E) {
    int idx = blockIdx.x * 256 + threadIdx.x;
    int e = idx >> 5, cc = (idx & 31) * 4;
    if (e >= E) return;
    int s = ei[e], d = ei[E + e];
    float nrm = dinv[s] * dinv[d];
    float4 v = *(const float4*)(y + (size_t)s * FDIM + cc);
    float* dst = o + (size_t)d * FDIM + cc;
    atomicAdd(dst + 0, v.x * nrm);
    atomicAdd(dst + 1, v.y * nrm);
    atomicAdd(dst + 2, v.z * nrm);
    atomicAdd(dst + 3, v.w * nrm);
}

__global__ void relu_kernel(float* __restrict__ x, int n4) {
    int i = blockIdx.x * 256 + threadIdx.x;
    if (i < n4) {
        float4 v = ((float4*)x)[i];
        v.x = fmaxf(v.x, 0.f); v.y = fmaxf(v.y, 0.f);
        v.z = fmaxf(v.z, 0.f); v.w = fmaxf(v.w, 0.f);
        ((float4*)x)[i] = v;
    }
}

// ---------------------------------------------------------------------------
// LSTM v6: fp16 weights pinned in AGPRs ("a" inline-asm constraint — the
// unified gfx950 register file's AGPR side is NOT subject to the VGPR-pressure
// heuristic that spilled v2-v5's weight arrays to scratch, 88->80->60->44).
// Init: global_load -> v_accvgpr_write (32 AGPRs/thread). Step loop:
// volatile v_accvgpr_read just-in-time (cannot be hoisted into 32 live
// VGPRs) -> v_dot2_f32_f16. Zero per-step memory traffic for weights.
// Topology as v5: 1024 threads, thread (w=t>>7, j=t&127) = 4 gate rows of
// hidden index j over K-slice [16w,16w+16); h fp16 in LDS (broadcast b128);
// partials part[w][j*4] lane-contiguous; phase B on 2 waves. 2 barriers/step.
// ---------------------------------------------------------------------------
#define AGPR_STASH8(P, A0, A1, A2, A3, A4, A5, A6, A7)                          \
    do {                                                                        \
        float t0, t1, t2, t3, t4, t5, t6, t7;                                   \
        asm volatile("global_load_dword %0, %1, off" : "=v"(t0) : "v"((P) + 0));\
        asm volatile("global_load_dword %0, %1, off" : "=v"(t1) : "v"((P) + 1));\
        asm volatile("global_load_dword %0, %1, off" : "=v"(t2) : "v"((P) + 2));\
        asm volatile("global_load_dword %0, %1, off" : "=v"(t3) : "v"((P) + 3));\
        asm volatile("global_load_dword %0, %1, off" : "=v"(t4) : "v"((P) + 4));\
        asm volatile("global_load_dword %0, %1, off" : "=v"(t5) : "v"((P) + 5));\
        asm volatile("global_load_dword %0, %1, off" : "=v"(t6) : "v"((P) + 6));\
        asm volatile("global_load_dword %0, %1, off" : "=v"(t7) : "v"((P) + 7));\
        asm volatile("s_waitcnt vmcnt(0)" ::: "memory");                        \
        asm volatile("v_accvgpr_write_b32 %0, %1" : "=a"(A0) : "v"(t0));        \
        asm volatile("v_accvgpr_write_b32 %0, %1" : "=a"(A1) : "v"(t1));        \
        asm volatile("v_accvgpr_write_b32 %0, %1" : "=a"(A2) : "v"(t2));        \
        asm volatile("v_accvgpr_write_b32 %0, %1" : "=a"(A3) : "v"(t3));        \
        asm volatile("v_accvgpr_write_b32 %0, %1" : "=a"(A4) : "v"(t4));        \
        asm volatile("v_accvgpr_write_b32 %0, %1" : "=a"(A5) : "v"(t5));        \
        asm volatile("v_accvgpr_write_b32 %0, %1" : "=a"(A6) : "v"(t6));        \
        asm volatile("v_accvgpr_write_b32 %0, %1" : "=a"(A7) : "v"(t7));        \
    } while (0)

#define DOT_A(AREG, ACC, HV)                                                    \
    do {                                                                        \
        float wv_;                                                              \
        asm volatile("v_accvgpr_read_b32 %0, %1" : "=v"(wv_) : "a"(AREG));      \
        asm("v_dot2_f32_f16 %0, %1, %2, %0" : "+v"(ACC) : "v"(wv_), "v"(HV));   \
    } while (0)

#define DOT4G(MM, HV)                                                           \
    DOT_A(w0_##MM, acc0, HV); DOT_A(w1_##MM, acc1, HV);                         \
    DOT_A(w2_##MM, acc2, HV); DOT_A(w3_##MM, acc3, HV);

__global__ void __launch_bounds__(1024)
lstm_kernel(const float* __restrict__ xg, const float* __restrict__ whp,
            float* __restrict__ hs, int T) {
    __shared__ __align__(16) __half hl[FDIM];   // fp16 hidden state
    __shared__ float part[8][520];              // [slice][j*4+gate]
    const int t = threadIdx.x;
    const int j = t & 127;
    const int w = t >> 7;                       // slice id 0..7, wave-uniform

    // 32 packed half2 weights pinned in AGPRs.
    float w0_0, w0_1, w0_2, w0_3, w0_4, w0_5, w0_6, w0_7;
    float w1_0, w1_1, w1_2, w1_3, w1_4, w1_5, w1_6, w1_7;
    float w2_0, w2_1, w2_2, w2_3, w2_4, w2_5, w2_6, w2_7;
    float w3_0, w3_1, w3_2, w3_3, w3_4, w3_5, w3_6, w3_7;
    {
        const float* base = whp + j * 64 + w * 8;    // whp row = g*128+j, 64 half2/row
        const float* p0 = base + 0 * (FDIM * 64);
        const float* p1 = base + 1 * (FDIM * 64);
        const float* p2 = base + 2 * (FDIM * 64);
        const float* p3 = base + 3 * (FDIM * 64);
        AGPR_STASH8(p0, w0_0, w0_1, w0_2, w0_3, w0_4, w0_5, w0_6, w0_7);
        AGPR_STASH8(p1, w1_0, w1_1, w1_2, w1_3, w1_4, w1_5, w1_6, w1_7);
        AGPR_STASH8(p2, w2_0, w2_1, w2_2, w2_3, w2_4, w2_5, w2_6, w2_7);
        AGPR_STASH8(p3, w3_0, w3_1, w3_2, w3_3, w3_4, w3_5, w3_6, w3_7);
    }

    float c = 0.f;
    float xv0[4], xv1[4];
    if (t < FDIM) {
        hl[t] = __float2half(0.f);
        #pragma unroll
        for (int g = 0; g < 4; ++g) {
            xv0[g] = xg[g * FDIM + t];
            xv1[g] = xg[G4H + g * FDIM + t];
        }
    }
    __syncthreads();

    for (int step = 0; step < T; ++step) {
        // ---- phase A: partial GEMV via AGPR-read + v_dot2_f32_f16 ----
        const float* hb = (const float*)hl + w * 8;  // 16 halves = 8 dwords, wave-uniform
        float4 hqA = *(const float4*)(hb + 0);
        float4 hqB = *(const float4*)(hb + 4);
        float acc0 = 0.f, acc1 = 0.f, acc2 = 0.f, acc3 = 0.f;
        DOT4G(0, hqA.x); DOT4G(1, hqA.y); DOT4G(2, hqA.z); DOT4G(3, hqA.w);
        DOT4G(4, hqB.x); DOT4G(5, hqB.y); DOT4G(6, hqB.z); DOT4G(7, hqB.w);
        *(float4*)&part[w][j * 4] = make_float4(acc0, acc1, acc2, acc3);
        __syncthreads();

        // ---- phase B: 2 waves, thread j: combine + activations + state ----
        if (t < FDIM) {
            float4 s0 = *(const float4*)&part[0][t * 4];
            float4 s1 = *(const float4*)&part[1][t * 4];
            float4 a01 = make_float4(s0.x + s1.x, s0.y + s1.y, s0.z + s1.z, s0.w + s1.w);
            float4 s2 = *(const float4*)&part[2][t * 4];
            float4 s3 = *(const float4*)&part[3][t * 4];
            float4 a23 = make_float4(s2.x + s3.x, s2.y + s3.y, s2.z + s3.z, s2.w + s3.w);
            float4 s4 = *(const float4*)&part[4][t * 4];
            float4 s5 = *(const float4*)&part[5][t * 4];
            float4 a45 = make_float4(s4.x + s5.x, s4.y + s5.y, s4.z + s5.z, s4.w + s5.w);
            float4 s6 = *(const float4*)&part[6][t * 4];
            float4 s7 = *(const float4*)&part[7][t * 4];
            float4 a67 = make_float4(s6.x + s7.x, s6.y + s7.y, s6.z + s7.z, s6.w + s7.w);
            float gi = (a01.x + a23.x) + (a45.x + a67.x) + xv0[0];
            float gf = (a01.y + a23.y) + (a45.y + a67.y) + xv0[1];
            float gg = (a01.z + a23.z) + (a45.z + a67.z) + xv0[2];
            float go = (a01.w + a23.w) + (a45.w + a67.w) + xv0[3];
            // rotate xg prefetch (2-deep)
            #pragma unroll
            for (int g = 0; g < 4; ++g) xv0[g] = xv1[g];
            if (step + 2 < T) {
                #pragma unroll
                for (int g = 0; g < 4; ++g)
                    xv1[g] = xg[(size_t)(step + 2) * G4H + g * FDIM + t];
            }
            gi = 1.f / (1.f + __expf(-gi));
            gf = 1.f / (1.f + __expf(-gf));
            gg = 1.f - 2.f / (1.f + __expf(2.f * gg));
            go = 1.f / (1.f + __expf(-go));
            c = gf * c + gi * gg;
            float th = 1.f - 2.f / (1.f + __expf(2.f * c));
            float h = go * th;
            hs[(size_t)step * FDIM + t] = h;
            hl[t] = __float2half(h);
        }
        __syncthreads();
    }
}

// ---------------------------------------------------------------------------
// out[M x 12] = hs[M x 128] @ w_fc^T + b_fc
// ---------------------------------------------------------------------------
__global__ __launch_bounds__(256) void fc_kernel(const float* __restrict__ hs,
                                                 const float* __restrict__ wfc,
                                                 const float* __restrict__ bfc,
                                                 float* __restrict__ out, int M) {
    __shared__ float wl[12 * FDIM];
    __shared__ float bl[12];
    const int tid = threadIdx.x;
    for (int i = tid; i < 12 * FDIM / 4; i += 256)
        ((float4*)wl)[i] = ((const float4*)wfc)[i];
    if (tid < 12) bl[tid] = bfc[tid];
    __syncthreads();

    int i = blockIdx.x * 256 + tid;
    if (i >= M) return;
    const float* hrow = hs + (size_t)i * FDIM;
    float acc[12];
    #pragma unroll
    for (int t = 0; t < 12; ++t) acc[t] = bl[t];
    for (int k = 0; k < FDIM; k += 4) {
        float4 h4 = *(const float4*)(hrow + k);
        #pragma unroll
        for (int t = 0; t < 12; ++t) {
            acc[t] += h4.x * wl[t * FDIM + k] + h4.y * wl[t * FDIM + k + 1]
                    + h4.z * wl[t * FDIM + k + 2] + h4.w * wl[t * FDIM + k + 3];
        }
    }
    #pragma unroll
    for (int t = 0; t < 12; ++t) out[(size_t)i * 12 + t] = acc[t];
}

// ---------------------------------------------------------------------------
extern "C" void kernel_launch(void* const* d_in, const int* in_sizes, int n_in,
                              void* d_out, int out_size, void* d_ws, size_t ws_size,
                              hipStream_t stream) {
    const float* x    = (const float*)d_in[0];
    const int*   ei   = (const int*)  d_in[1];
    const float* W1   = (const float*)d_in[2];
    const float* b1   = (const float*)d_in[3];
    const float* W2   = (const float*)d_in[4];
    const float* b2   = (const float*)d_in[5];
    const float* w_ih = (const float*)d_in[6];
    const float* w_hh = (const float*)d_in[7];
    const float* b_ih = (const float*)d_in[8];
    const float* b_hh = (const float*)d_in[9];
    const float* w_fc = (const float*)d_in[10];
    const float* b_fc = (const float*)d_in[11];

    const int N = in_sizes[0] / FDIM;     // 20000
    const int E = in_sizes[1] / 2;        // 1280000

    float* ws   = (float*)d_ws;
    int*   deg  = (int*)ws;               // [0, 20480) ints
    float* dinv = ws + 20480;
    float* whp  = ws + 40960;             // packed fp16 w_hh: 512*64 slots
    float* hB   = ws + 40960 + 32768;     // h2: N*128
    float* big  = hB + (size_t)N * FDIM;  // xg region (N*512), aliases y/hA
    float* y    = big;                    // N*128 (dead before xg written)
    float* hA   = big + (size_t)N * FDIM; // h1   (dead before xg written)
    float* xg   = big;                    // N*512
    float* hs   = big + (size_t)N * G4H;  // N*128

    hipMemsetAsync(deg, 0, (size_t)N * sizeof(int), stream);
    deg_kernel<<<(E + 255) / 256, 256, 0, stream>>>(ei, deg, E);
    dinv_kernel<<<(N + 255) / 256, 256, 0, stream>>>(deg, dinv, N);
    pack_whh<<<(512 * 64 + 255) / 256, 256, 0, stream>>>(w_hh, whp, 512 * 64);

    const int gblocks = (N + 31) / 32;
    // layer 1
    gemm_nn<<<gblocks, 256, 0, stream>>>(x, W1, y, N);
    agg_init<<<(N * 32 + 255) / 256, 256, 0, stream>>>(y, dinv, b1, hA, N);
    agg_edges<<<(E * 32 + 255) / 256, 256, 0, stream>>>(y, ei, dinv, hA, E);
    relu_kernel<<<(N * 32 + 255) / 256, 256, 0, stream>>>(hA, N * 32);
    // layer 2
    gemm_nn<<<gblocks, 256, 0, stream>>>(hA, W2, y, N);
    agg_init<<<(N * 32 + 255) / 256, 256, 0, stream>>>(y, dinv, b2, hB, N);
    agg_edges<<<(E * 32 + 255) / 256, 256, 0, stream>>>(y, ei, dinv, hB, E);
    relu_kernel<<<(N * 32 + 255) / 256, 256, 0, stream>>>(hB, N * 32);
    // LSTM input projection
    gemm_nt_xg<<<dim3(gblocks, 4), 256, 0, stream>>>(hB, w_ih, b_ih, b_hh, xg, N);
    // sequential LSTM (single CU — the critical path)
    lstm_kernel<<<1, 1024, 0, stream>>>(xg, whp, hs, N);
    // final projection
    fc_kernel<<<(N + 255) / 256, 256, 0, stream>>>(hs, w_fc, b_fc, (float*)d_out, N);
}

// Round 7
// 21670.811 us; speedup vs baseline: 1.1891x; 1.1891x over previous
//
#include <hip/hip_runtime.h>
#include <hip/hip_bf16.h>
#include <hip/hip_fp16.h>

// Problem constants (fixed by the reference)
#define FDIM 128      // F_IN == H == 128
#define G4H  512      // 4*H

typedef float f32x4 __attribute__((ext_vector_type(4)));
typedef _Float16 f16x8 __attribute__((ext_vector_type(8)));

union frag_cast { f32x4 f; f16x8 h; };

// ---------------------------------------------------------------------------
// degree / normalization
// ---------------------------------------------------------------------------
__global__ void deg_kernel(const int* __restrict__ ei, int* __restrict__ deg, int E) {
    int e = blockIdx.x * 256 + threadIdx.x;
    if (e < E) atomicAdd(&deg[ei[E + e]], 1);
}

__global__ void dinv_kernel(const int* __restrict__ deg, float* __restrict__ dinv, int N) {
    int n = blockIdx.x * 256 + threadIdx.x;
    if (n < N) dinv[n] = rsqrtf((float)(deg[n] + 1));   // +1 self-loop
}

// ---------------------------------------------------------------------------
// Prepack w_hh [512 x 128] fp32 into fp16 MFMA A-fragments.
// Fragment order: dword idx = (((w*4+rt)*4+kt)*64 + lane)*4 + d
//   wave w: gate rows [64w, 64w+64); row-tile rt: 16 rows; K-tile kt: 32 k.
//   lane: m = lane&15 (row in tile), q = lane>>4 (k-quad).
//   A[m][k]: lane holds halves k = 32kt + 8q + {2d, 2d+1}, row 64w+16rt+m.
// ---------------------------------------------------------------------------
__global__ void pack_whh(const float* __restrict__ whh, float* __restrict__ whp, int n) {
    int i = blockIdx.x * 256 + threadIdx.x;   // n = 32768 dwords
    if (i >= n) return;
    int d = i & 3, fi = i >> 2;
    int lane = fi & 63, kt = (fi >> 6) & 3, rt = (fi >> 8) & 3, w = fi >> 10;
    int m = lane & 15, q = lane >> 4;
    int r = 64 * w + 16 * rt + m;
    int k = 32 * kt + 8 * q + 2 * d;
    __half lo = __float2half(whh[r * FDIM + k]);
    __half hi = __float2half(whh[r * FDIM + k + 1]);
    unsigned u = ((unsigned)__half_as_ushort(hi) << 16) | (unsigned)__half_as_ushort(lo);
    whp[i] = __uint_as_float(u);
}

// ---------------------------------------------------------------------------
// C[M x 128] = A[M x 128] @ B[128 x 128]   (B is K-major: B[k*128 + j])
// ---------------------------------------------------------------------------
__global__ __launch_bounds__(256) void gemm_nn(const float* __restrict__ A,
                                               const float* __restrict__ B,
                                               float* __restrict__ C, int M) {
    __shared__ float Bl[64 * 132];
    __shared__ float Al[32][FDIM];
    const int tid = threadIdx.x;
    const int row0 = blockIdx.x * 32;

    for (int i = tid * 4; i < 32 * FDIM; i += 1024) {
        int r = i >> 7, k = i & 127;
        int row = row0 + r;
        float4 v = make_float4(0.f, 0.f, 0.f, 0.f);
        if (row < M) v = *(const float4*)(A + (size_t)row * FDIM + k);
        *(float4*)&Al[r][k] = v;
    }

    const int jg = tid & 31, rg = tid >> 5;
    float acc[4][4] = {};

    for (int kh = 0; kh < 2; ++kh) {
        __syncthreads();
        for (int i = tid * 4; i < 64 * FDIM; i += 1024) {
            int k = i >> 7, j = i & 127;
            *(float4*)&Bl[k * 132 + j] = *(const float4*)(B + (size_t)(kh * 64 + k) * FDIM + j);
        }
        __syncthreads();
        #pragma unroll 4
        for (int k = 0; k < 64; ++k) {
            float4 b4 = *(const float4*)&Bl[k * 132 + jg * 4];
            #pragma unroll
            for (int rr = 0; rr < 4; ++rr) {
                float a = Al[rg * 4 + rr][kh * 64 + k];
                acc[rr][0] += a * b4.x; acc[rr][1] += a * b4.y;
                acc[rr][2] += a * b4.z; acc[rr][3] += a * b4.w;
            }
        }
    }
    #pragma unroll
    for (int rr = 0; rr < 4; ++rr) {
        int row = row0 + rg * 4 + rr;
        if (row < M) {
            float4 v = make_float4(acc[rr][0], acc[rr][1], acc[rr][2], acc[rr][3]);
            *(float4*)(C + (size_t)row * FDIM + jg * 4) = v;
        }
    }
}

// ---------------------------------------------------------------------------
// xg[M x 512] = A[M x 128] @ B^T  (+ b_ih + b_hh), B is [512 x 128] row-major.
// ---------------------------------------------------------------------------
__global__ __launch_bounds__(256) void gemm_nt_xg(const float* __restrict__ A,
                                                  const float* __restrict__ B,
                                                  const float* __restrict__ bih,
                                                  const float* __restrict__ bhh,
                                                  float* __restrict__ C, int M) {
    __shared__ float Bl[64 * 132];
    __shared__ float Al[32][FDIM];
    const int tid = threadIdx.x;
    const int row0 = blockIdx.x * 32;
    const int chunk = blockIdx.y;

    for (int i = tid * 4; i < 32 * FDIM; i += 1024) {
        int r = i >> 7, k = i & 127;
        int row = row0 + r;
        float4 v = make_float4(0.f, 0.f, 0.f, 0.f);
        if (row < M) v = *(const float4*)(A + (size_t)row * FDIM + k);
        *(float4*)&Al[r][k] = v;
    }

    const int jg = tid & 31, rg = tid >> 5;
    float acc[4][4] = {};

    for (int kh = 0; kh < 2; ++kh) {
        __syncthreads();
        for (int i = tid * 4; i < 128 * 64; i += 1024) {
            int g = i >> 6, kl = i & 63;
            float4 v = *(const float4*)(B + (size_t)(chunk * 128 + g) * FDIM + kh * 64 + kl);
            Bl[(kl + 0) * 132 + g] = v.x;
            Bl[(kl + 1) * 132 + g] = v.y;
            Bl[(kl + 2) * 132 + g] = v.z;
            Bl[(kl + 3) * 132 + g] = v.w;
        }
        __syncthreads();
        #pragma unroll 4
        for (int k = 0; k < 64; ++k) {
            float4 b4 = *(const float4*)&Bl[k * 132 + jg * 4];
            #pragma unroll
            for (int rr = 0; rr < 4; ++rr) {
                float a = Al[rg * 4 + rr][kh * 64 + k];
                acc[rr][0] += a * b4.x; acc[rr][1] += a * b4.y;
                acc[rr][2] += a * b4.z; acc[rr][3] += a * b4.w;
            }
        }
    }
    const int col0 = chunk * 128 + jg * 4;
    float4 bsum = make_float4(bih[col0 + 0] + bhh[col0 + 0],
                              bih[col0 + 1] + bhh[col0 + 1],
                              bih[col0 + 2] + bhh[col0 + 2],
                              bih[col0 + 3] + bhh[col0 + 3]);
    #pragma unroll
    for (int rr = 0; rr < 4; ++rr) {
        int row = row0 + rg * 4 + rr;
        if (row < M) {
            float4 v = make_float4(acc[rr][0] + bsum.x, acc[rr][1] + bsum.y,
                                   acc[rr][2] + bsum.z, acc[rr][3] + bsum.w);
            *(float4*)(C + (size_t)row * G4H + col0) = v;
        }
    }
}

// ---------------------------------------------------------------------------
// GCN aggregation
// ---------------------------------------------------------------------------
__global__ void agg_init(const float* __restrict__ y, const float* __restrict__ dinv,
                         const float* __restrict__ bias, float* __restrict__ o, int N) {
    int idx = blockIdx.x * 256 + threadIdx.x;
    int n = idx >> 5, cc = (idx & 31) * 4;
    if (n >= N) return;
    float s = dinv[n]; s = s * s;
    float4 v = *(const float4*)(y + (size_t)n * FDIM + cc);
    float4 b = *(const float4*)(bias + cc);
    float4 r = make_float4(v.x * s + b.x, v.y * s + b.y, v.z * s + b.z, v.w * s + b.w);
    *(float4*)(o + (size_t)n * FDIM + cc) = r;
}

__global__ void agg_edges(const float* __restrict__ y, const int* __restrict__ ei,
                          const float* __restrict__ dinv, float* __restrict__ o, int E) {
    int idx = blockIdx.x * 256 + threadIdx.x;
    int e = idx >> 5, cc = (idx & 31) * 4;
    if (e >= E) return;
    int s = ei[e], d = ei[E + e];
    float nrm = dinv[s] * dinv[d];
    float4 v = *(const float4*)(y + (size_t)s * FDIM + cc);
    float* dst = o + (size_t)d * FDIM + cc;
    atomicAdd(dst + 0, v.x * nrm);
    atomicAdd(dst + 1, v.y * nrm);
    atomicAdd(dst + 2, v.z * nrm);
    atomicAdd(dst + 3, v.w * nrm);
}

__global__ void relu_kernel(float* __restrict__ x, int n4) {
    int i = blockIdx.x * 256 + threadIdx.x;
    if (i < n4) {
        float4 v = ((float4*)x)[i];
        v.x = fmaxf(v.x, 0.f); v.y = fmaxf(v.y, 0.f);
        v.z = fmaxf(v.z, 0.f); v.w = fmaxf(v.w, 0.f);
        ((float4*)x)[i] = v;
    }
}

// ---------------------------------------------------------------------------
// LSTM v7: MFMA GEMV with weights in AGPRs, consumed DIRECTLY by the matrix
// pipe (no accvgpr_read tax — v6's 1330 cyc/step VALU bill).
// 512 threads = 8 waves. Wave w owns gate rows [64w,64w+64) = gate (w>>1),
// j-half (w&1): 4 row-tiles x 4 K-tiles of v_mfma_f32_16x16x32_f16.
// A-frags (64 AGPRs/thread) pinned via empty-asm "=a" tie (residency proven
// in v6), consumed by the builtin (AV-class operands, hazards handled).
// B = h (fp16, LDS) broadcast to all 16 cols -> every C col holds the full
// gate preactivations; K-accum inside C kills cross-wave reduction.
// Writeout: lanes n<4 select cd[n] (cndmask) -> one ds_write_b128/wave.
// Phase B: 2 waves, thread j: 4 b32 gate reads + xg (2-deep prefetch),
// activations fp32, c_j in register, write h (fp16 LDS) + hs (global).
// ---------------------------------------------------------------------------
__global__ void __launch_bounds__(512, 2)
lstm_kernel(const float* __restrict__ xg, const float* __restrict__ whp,
            float* __restrict__ hs, int T) {
    __shared__ __align__(16) __half hl[FDIM];
    __shared__ __align__(16) float gates[4 * 136];   // stride 136 floats per gate
    const int t = threadIdx.x;
    const int w = t >> 6;          // wave 0..7
    const int lane = t & 63;
    const int q = lane >> 4;       // k-quad / C row-quad
    const int n = lane & 15;       // C column

    // Load + pin A-fragments into AGPRs: aw[rt][kt], 4 dwords (8 fp16) each.
    f16x8 aw[4][4];
    {
        const f32x4* wp4 = (const f32x4*)whp;
        #pragma unroll
        for (int rt = 0; rt < 4; ++rt) {
            #pragma unroll
            for (int kt = 0; kt < 4; ++kt) {
                frag_cast fc;
                fc.f = wp4[((w * 4 + rt) * 4 + kt) * 64 + lane];
                f16x8 tmp = fc.h;
                asm volatile("" : "=a"(aw[rt][kt]) : "0"(tmp));  // pin to AGPR class
            }
        }
    }

    float c = 0.f;
    float xv0[4], xv1[4];
    if (t < FDIM) {
        hl[t] = __float2half(0.f);
        #pragma unroll
        for (int g = 0; g < 4; ++g) {
            xv0[g] = xg[g * FDIM + t];
            xv1[g] = xg[G4H + g * FDIM + t];
        }
    }
    __syncthreads();

    const int gsel = w >> 1;                     // this wave's gate
    const int j0 = (w & 1) * 64 + 16 * n + 4 * q; // writeout j (lanes n<4)

    for (int step = 0; step < T; ++step) {
        // ---- phase A: MFMA GEMV, all 8 waves ----
        f32x4 cd0 = {0.f, 0.f, 0.f, 0.f}, cd1 = cd0, cd2 = cd0, cd3 = cd0;
        #pragma unroll
        for (int kt = 0; kt < 4; ++kt) {
            // B-frag: h[32kt + 8q .. +8) broadcast to all 16 columns.
            frag_cast bc;
            bc.f = *(const f32x4*)((const char*)hl + kt * 64 + q * 16);
            f16x8 b = bc.h;
            cd0 = __builtin_amdgcn_mfma_f32_16x16x32_f16(aw[0][kt], b, cd0, 0, 0, 0);
            cd1 = __builtin_amdgcn_mfma_f32_16x16x32_f16(aw[1][kt], b, cd1, 0, 0, 0);
            cd2 = __builtin_amdgcn_mfma_f32_16x16x32_f16(aw[2][kt], b, cd2, 0, 0, 0);
            cd3 = __builtin_amdgcn_mfma_f32_16x16x32_f16(aw[3][kt], b, cd3, 0, 0, 0);
        }
        // Every C column holds the same values; lanes n<4 write row-tile rt=n.
        f32x4 sel = (n == 0) ? cd0 : (n == 1) ? cd1 : (n == 2) ? cd2 : cd3;
        if (n < 4)
            *(f32x4*)&gates[gsel * 136 + j0] = sel;
        __syncthreads();

        // ---- phase B: 2 waves, thread j: combine + activations + state ----
        if (t < FDIM) {
            float gi = gates[0 * 136 + t] + xv0[0];
            float gf = gates[1 * 136 + t] + xv0[1];
            float gg = gates[2 * 136 + t] + xv0[2];
            float go = gates[3 * 136 + t] + xv0[3];
            // rotate xg prefetch (2-deep)
            #pragma unroll
            for (int g = 0; g < 4; ++g) xv0[g] = xv1[g];
            if (step + 2 < T) {
                #pragma unroll
                for (int g = 0; g < 4; ++g)
                    xv1[g] = xg[(size_t)(step + 2) * G4H + g * FDIM + t];
            }
            gi = 1.f / (1.f + __expf(-gi));
            gf = 1.f / (1.f + __expf(-gf));
            gg = 1.f - 2.f / (1.f + __expf(2.f * gg));
            go = 1.f / (1.f + __expf(-go));
            c = gf * c + gi * gg;
            float th = 1.f - 2.f / (1.f + __expf(2.f * c));
            float h = go * th;
            hs[(size_t)step * FDIM + t] = h;
            hl[t] = __float2half(h);
        }
        __syncthreads();
    }
}

// ---------------------------------------------------------------------------
// out[M x 12] = hs[M x 128] @ w_fc^T + b_fc
// ---------------------------------------------------------------------------
__global__ __launch_bounds__(256) void fc_kernel(const float* __restrict__ hs,
                                                 const float* __restrict__ wfc,
                                                 const float* __restrict__ bfc,
                                                 float* __restrict__ out, int M) {
    __shared__ float wl[12 * FDIM];
    __shared__ float bl[12];
    const int tid = threadIdx.x;
    for (int i = tid; i < 12 * FDIM / 4; i += 256)
        ((float4*)wl)[i] = ((const float4*)wfc)[i];
    if (tid < 12) bl[tid] = bfc[tid];
    __syncthreads();

    int i = blockIdx.x * 256 + tid;
    if (i >= M) return;
    const float* hrow = hs + (size_t)i * FDIM;
    float acc[12];
    #pragma unroll
    for (int t = 0; t < 12; ++t) acc[t] = bl[t];
    for (int k = 0; k < FDIM; k += 4) {
        float4 h4 = *(const float4*)(hrow + k);
        #pragma unroll
        for (int t = 0; t < 12; ++t) {
            acc[t] += h4.x * wl[t * FDIM + k] + h4.y * wl[t * FDIM + k + 1]
                    + h4.z * wl[t * FDIM + k + 2] + h4.w * wl[t * FDIM + k + 3];
        }
    }
    #pragma unroll
    for (int t = 0; t < 12; ++t) out[(size_t)i * 12 + t] = acc[t];
}

// ---------------------------------------------------------------------------
extern "C" void kernel_launch(void* const* d_in, const int* in_sizes, int n_in,
                              void* d_out, int out_size, void* d_ws, size_t ws_size,
                              hipStream_t stream) {
    const float* x    = (const float*)d_in[0];
    const int*   ei   = (const int*)  d_in[1];
    const float* W1   = (const float*)d_in[2];
    const float* b1   = (const float*)d_in[3];
    const float* W2   = (const float*)d_in[4];
    const float* b2   = (const float*)d_in[5];
    const float* w_ih = (const float*)d_in[6];
    const float* w_hh = (const float*)d_in[7];
    const float* b_ih = (const float*)d_in[8];
    const float* b_hh = (const float*)d_in[9];
    const float* w_fc = (const float*)d_in[10];
    const float* b_fc = (const float*)d_in[11];

    const int N = in_sizes[0] / FDIM;     // 20000
    const int E = in_sizes[1] / 2;        // 1280000

    float* ws   = (float*)d_ws;
    int*   deg  = (int*)ws;               // [0, 20480) ints
    float* dinv = ws + 20480;
    float* whp  = ws + 40960;             // MFMA-packed fp16 w_hh: 32768 dwords
    float* hB   = ws + 40960 + 32768;     // h2: N*128
    float* big  = hB + (size_t)N * FDIM;  // xg region (N*512), aliases y/hA
    float* y    = big;                    // N*128 (dead before xg written)
    float* hA   = big + (size_t)N * FDIM; // h1   (dead before xg written)
    float* xg   = big;                    // N*512
    float* hs   = big + (size_t)N * G4H;  // N*128

    hipMemsetAsync(deg, 0, (size_t)N * sizeof(int), stream);
    deg_kernel<<<(E + 255) / 256, 256, 0, stream>>>(ei, deg, E);
    dinv_kernel<<<(N + 255) / 256, 256, 0, stream>>>(deg, dinv, N);
    pack_whh<<<(32768 + 255) / 256, 256, 0, stream>>>(w_hh, whp, 32768);

    const int gblocks = (N + 31) / 32;
    // layer 1
    gemm_nn<<<gblocks, 256, 0, stream>>>(x, W1, y, N);
    agg_init<<<(N * 32 + 255) / 256, 256, 0, stream>>>(y, dinv, b1, hA, N);
    agg_edges<<<(E * 32 + 255) / 256, 256, 0, stream>>>(y, ei, dinv, hA, E);
    relu_kernel<<<(N * 32 + 255) / 256, 256, 0, stream>>>(hA, N * 32);
    // layer 2
    gemm_nn<<<gblocks, 256, 0, stream>>>(hA, W2, y, N);
    agg_init<<<(N * 32 + 255) / 256, 256, 0, stream>>>(y, dinv, b2, hB, N);
    agg_edges<<<(E * 32 + 255) / 256, 256, 0, stream>>>(y, ei, dinv, hB, E);
    relu_kernel<<<(N * 32 + 255) / 256, 256, 0, stream>>>(hB, N * 32);
    // LSTM input projection
    gemm_nt_xg<<<dim3(gblocks, 4), 256, 0, stream>>>(hB, w_ih, b_ih, b_hh, xg, N);
    // sequential LSTM (single CU — the critical path)
    lstm_kernel<<<1, 512, 0, stream>>>(xg, whp, hs, N);
    // final projection
    fc_kernel<<<(N + 255) / 256, 256, 0, stream>>>(hs, w_fc, b_fc, (float*)d_out, N);
}

// Round 8
// 18876.900 us; speedup vs baseline: 1.3650x; 1.1480x over previous
//
#include <hip/hip_runtime.h>
#include <hip/hip_bf16.h>
#include <hip/hip_fp16.h>

// Problem constants (fixed by the reference)
#define FDIM 128      // F_IN == H == 128
#define G4H  512      // 4*H

typedef float f32x4 __attribute__((ext_vector_type(4)));
typedef _Float16 f16x8 __attribute__((ext_vector_type(8)));

union frag_cast { f32x4 f; f16x8 h; };

// LDS-only barrier: does NOT drain vmcnt (global xg prefetch / hs stores stay
// in flight across the barrier — __syncthreads() drains vmcnt(0), which put a
// ~900-cyc HBM round-trip inside every LSTM step in v1..v7).
#define LDS_BARRIER() asm volatile("s_waitcnt lgkmcnt(0)\n\ts_barrier" ::: "memory")

// ---------------------------------------------------------------------------
// degree / normalization
// ---------------------------------------------------------------------------
__global__ void deg_kernel(const int* __restrict__ ei, int* __restrict__ deg, int E) {
    int e = blockIdx.x * 256 + threadIdx.x;
    if (e < E) atomicAdd(&deg[ei[E + e]], 1);
}

__global__ void dinv_kernel(const int* __restrict__ deg, float* __restrict__ dinv, int N) {
    int n = blockIdx.x * 256 + threadIdx.x;
    if (n < N) dinv[n] = rsqrtf((float)(deg[n] + 1));   // +1 self-loop
}

// ---------------------------------------------------------------------------
// Prepack w_hh [512 x 128] fp32 into fp16 MFMA A-fragments.
// dword idx = (((w*4+rt)*4+kt)*64 + lane)*4 + d
//   lane: m = lane&15 (row in tile), q = lane>>4 (k-quad).
//   A[m][k]: lane holds halves k = 32kt + 8q + {2d, 2d+1}, row 64w+16rt+m.
// ---------------------------------------------------------------------------
__global__ void pack_whh(const float* __restrict__ whh, float* __restrict__ whp, int n) {
    int i = blockIdx.x * 256 + threadIdx.x;   // n = 32768 dwords
    if (i >= n) return;
    int d = i & 3, fi = i >> 2;
    int lane = fi & 63, kt = (fi >> 6) & 3, rt = (fi >> 8) & 3, w = fi >> 10;
    int m = lane & 15, q = lane >> 4;
    int r = 64 * w + 16 * rt + m;
    int k = 32 * kt + 8 * q + 2 * d;
    __half lo = __float2half(whh[r * FDIM + k]);
    __half hi = __float2half(whh[r * FDIM + k + 1]);
    unsigned u = ((unsigned)__half_as_ushort(hi) << 16) | (unsigned)__half_as_ushort(lo);
    whp[i] = __uint_as_float(u);
}

// ---------------------------------------------------------------------------
// C[M x 128] = A[M x 128] @ B[128 x 128]   (B is K-major: B[k*128 + j])
// ---------------------------------------------------------------------------
__global__ __launch_bounds__(256) void gemm_nn(const float* __restrict__ A,
                                               const float* __restrict__ B,
                                               float* __restrict__ C, int M) {
    __shared__ float Bl[64 * 132];
    __shared__ float Al[32][FDIM];
    const int tid = threadIdx.x;
    const int row0 = blockIdx.x * 32;

    for (int i = tid * 4; i < 32 * FDIM; i += 1024) {
        int r = i >> 7, k = i & 127;
        int row = row0 + r;
        float4 v = make_float4(0.f, 0.f, 0.f, 0.f);
        if (row < M) v = *(const float4*)(A + (size_t)row * FDIM + k);
        *(float4*)&Al[r][k] = v;
    }

    const int jg = tid & 31, rg = tid >> 5;
    float acc[4][4] = {};

    for (int kh = 0; kh < 2; ++kh) {
        __syncthreads();
        for (int i = tid * 4; i < 64 * FDIM; i += 1024) {
            int k = i >> 7, j = i & 127;
            *(float4*)&Bl[k * 132 + j] = *(const float4*)(B + (size_t)(kh * 64 + k) * FDIM + j);
        }
        __syncthreads();
        #pragma unroll 4
        for (int k = 0; k < 64; ++k) {
            float4 b4 = *(const float4*)&Bl[k * 132 + jg * 4];
            #pragma unroll
            for (int rr = 0; rr < 4; ++rr) {
                float a = Al[rg * 4 + rr][kh * 64 + k];
                acc[rr][0] += a * b4.x; acc[rr][1] += a * b4.y;
                acc[rr][2] += a * b4.z; acc[rr][3] += a * b4.w;
            }
        }
    }
    #pragma unroll
    for (int rr = 0; rr < 4; ++rr) {
        int row = row0 + rg * 4 + rr;
        if (row < M) {
            float4 v = make_float4(acc[rr][0], acc[rr][1], acc[rr][2], acc[rr][3]);
            *(float4*)(C + (size_t)row * FDIM + jg * 4) = v;
        }
    }
}

// ---------------------------------------------------------------------------
// xg[M x 512] = A[M x 128] @ B^T  (+ b_ih + b_hh), B is [512 x 128] row-major.
// ---------------------------------------------------------------------------
__global__ __launch_bounds__(256) void gemm_nt_xg(const float* __restrict__ A,
                                                  const float* __restrict__ B,
                                                  const float* __restrict__ bih,
                                                  const float* __restrict__ bhh,
                                                  float* __restrict__ C, int M) {
    __shared__ float Bl[64 * 132];
    __shared__ float Al[32][FDIM];
    const int tid = threadIdx.x;
    const int row0 = blockIdx.x * 32;
    const int chunk = blockIdx.y;

    for (int i = tid * 4; i < 32 * FDIM; i += 1024) {
        int r = i >> 7, k = i & 127;
        int row = row0 + r;
        float4 v = make_float4(0.f, 0.f, 0.f, 0.f);
        if (row < M) v = *(const float4*)(A + (size_t)row * FDIM + k);
        *(float4*)&Al[r][k] = v;
    }

    const int jg = tid & 31, rg = tid >> 5;
    float acc[4][4] = {};

    for (int kh = 0; kh < 2; ++kh) {
        __syncthreads();
        for (int i = tid * 4; i < 128 * 64; i += 1024) {
            int g = i >> 6, kl = i & 63;
            float4 v = *(const float4*)(B + (size_t)(chunk * 128 + g) * FDIM + kh * 64 + kl);
            Bl[(kl + 0) * 132 + g] = v.x;
            Bl[(kl + 1) * 132 + g] = v.y;
            Bl[(kl + 2) * 132 + g] = v.z;
            Bl[(kl + 3) * 132 + g] = v.w;
        }
        __syncthreads();
        #pragma unroll 4
        for (int k = 0; k < 64; ++k) {
            float4 b4 = *(const float4*)&Bl[k * 132 + jg * 4];
            #pragma unroll
            for (int rr = 0; rr < 4; ++rr) {
                float a = Al[rg * 4 + rr][kh * 64 + k];
                acc[rr][0] += a * b4.x; acc[rr][1] += a * b4.y;
                acc[rr][2] += a * b4.z; acc[rr][3] += a * b4.w;
            }
        }
    }
    const int col0 = chunk * 128 + jg * 4;
    float4 bsum = make_float4(bih[col0 + 0] + bhh[col0 + 0],
                              bih[col0 + 1] + bhh[col0 + 1],
                              bih[col0 + 2] + bhh[col0 + 2],
                              bih[col0 + 3] + bhh[col0 + 3]);
    #pragma unroll
    for (int rr = 0; rr < 4; ++rr) {
        int row = row0 + rg * 4 + rr;
        if (row < M) {
            float4 v = make_float4(acc[rr][0] + bsum.x, acc[rr][1] + bsum.y,
                                   acc[rr][2] + bsum.z, acc[rr][3] + bsum.w);
            *(float4*)(C + (size_t)row * G4H + col0) = v;
        }
    }
}

// ---------------------------------------------------------------------------
// GCN aggregation
// ---------------------------------------------------------------------------
__global__ void agg_init(const float* __restrict__ y, const float* __restrict__ dinv,
                         const float* __restrict__ bias, float* __restrict__ o, int N) {
    int idx = blockIdx.x * 256 + threadIdx.x;
    int n = idx >> 5, cc = (idx & 31) * 4;
    if (n >= N) return;
    float s = dinv[n]; s = s * s;
    float4 v = *(const float4*)(y + (size_t)n * FDIM + cc);
    float4 b = *(const float4*)(bias + cc);
    float4 r = make_float4(v.x * s + b.x, v.y * s + b.y, v.z * s + b.z, v.w * s + b.w);
    *(float4*)(o + (size_t)n * FDIM + cc) = r;
}

__global__ void agg_edges(const float* __restrict__ y, const int* __restrict__ ei,
                          const float* __restrict__ dinv, float* __restrict__ o, int E) {
    int idx = blockIdx.x * 256 + threadIdx.x;
    int e = idx >> 5, cc = (idx & 31) * 4;
    if (e >= E) return;
    int s = ei[e], d = ei[E + e];
    float nrm = dinv[s] * dinv[d];
    float4 v = *(const float4*)(y + (size_t)s * FDIM + cc);
    float* dst = o + (size_t)d * FDIM + cc;
    atomicAdd(dst + 0, v.x * nrm);
    atomicAdd(dst + 1, v.y * nrm);
    atomicAdd(dst + 2, v.z * nrm);
    atomicAdd(dst + 3, v.w * nrm);
}

__global__ void relu_kernel(float* __restrict__ x, int n4) {
    int i = blockIdx.x * 256 + threadIdx.x;
    if (i < n4) {
        float4 v = ((float4*)x)[i];
        v.x = fmaxf(v.x, 0.f); v.y = fmaxf(v.y, 0.f);
        v.z = fmaxf(v.z, 0.f); v.w = fmaxf(v.w, 0.f);
        ((float4*)x)[i] = v;
    }
}

// ---------------------------------------------------------------------------
// LSTM v8 = v7 (MFMA GEMV, AGPR-pinned fp16 weights) + LDS-only barriers.
// v7's plateau (2135 cyc/step) was the __syncthreads() vmcnt(0) drain: the
// in-step global ops (xg prefetch loads = HBM miss ~900 cyc, hs store) were
// forcibly drained inside every step. LDS_BARRIER waits lgkmcnt only; the
// only cross-thread data (gates, hl) is LDS. xg loads are consumed by the
// issuing thread; hs is read only by fc_kernel after kernel end.
// xg prefetch deepened to 3 steps (~2 full steps of slack per load).
// ---------------------------------------------------------------------------
__global__ void __launch_bounds__(512, 2)
lstm_kernel(const float* __restrict__ xg, const float* __restrict__ whp,
            float* __restrict__ hs, int T) {
    __shared__ __align__(16) __half hl[FDIM];
    __shared__ __align__(16) float gates[4 * 136];   // stride 136 floats per gate
    const int t = threadIdx.x;
    const int w = t >> 6;          // wave 0..7
    const int lane = t & 63;
    const int q = lane >> 4;       // k-quad / C row-quad
    const int n = lane & 15;       // C column

    // Load + pin A-fragments into AGPRs: aw[rt][kt], 4 dwords (8 fp16) each.
    f16x8 aw[4][4];
    {
        const f32x4* wp4 = (const f32x4*)whp;
        #pragma unroll
        for (int rt = 0; rt < 4; ++rt) {
            #pragma unroll
            for (int kt = 0; kt < 4; ++kt) {
                frag_cast fc;
                fc.f = wp4[((w * 4 + rt) * 4 + kt) * 64 + lane];
                f16x8 tmp = fc.h;
                asm volatile("" : "=a"(aw[rt][kt]) : "0"(tmp));  // pin to AGPR class
            }
        }
    }

    float c = 0.f;
    float xv0[4], xv1[4], xv2[4];
    if (t < FDIM) {
        hl[t] = __float2half(0.f);
        #pragma unroll
        for (int g = 0; g < 4; ++g) {
            xv0[g] = xg[g * FDIM + t];
            xv1[g] = xg[1 * G4H + g * FDIM + t];
            xv2[g] = xg[2 * G4H + g * FDIM + t];
        }
    }
    __syncthreads();

    const int gsel = w >> 1;                      // this wave's gate
    const int j0 = (w & 1) * 64 + 16 * n + 4 * q; // writeout j (lanes n<4)

    for (int step = 0; step < T; ++step) {
        // ---- phase A: MFMA GEMV, all 8 waves ----
        f32x4 cd0 = {0.f, 0.f, 0.f, 0.f}, cd1 = cd0, cd2 = cd0, cd3 = cd0;
        #pragma unroll
        for (int kt = 0; kt < 4; ++kt) {
            // B-frag: h[32kt + 8q .. +8) broadcast to all 16 columns.
            frag_cast bc;
            bc.f = *(const f32x4*)((const char*)hl + kt * 64 + q * 16);
            f16x8 b = bc.h;
            cd0 = __builtin_amdgcn_mfma_f32_16x16x32_f16(aw[0][kt], b, cd0, 0, 0, 0);
            cd1 = __builtin_amdgcn_mfma_f32_16x16x32_f16(aw[1][kt], b, cd1, 0, 0, 0);
            cd2 = __builtin_amdgcn_mfma_f32_16x16x32_f16(aw[2][kt], b, cd2, 0, 0, 0);
            cd3 = __builtin_amdgcn_mfma_f32_16x16x32_f16(aw[3][kt], b, cd3, 0, 0, 0);
        }
        // Every C column holds the same values; lanes n<4 write row-tile rt=n.
        f32x4 sel = (n == 0) ? cd0 : (n == 1) ? cd1 : (n == 2) ? cd2 : cd3;
        if (n < 4)
            *(f32x4*)&gates[gsel * 136 + j0] = sel;
        LDS_BARRIER();

        // ---- phase B: 2 waves, thread j: combine + activations + state ----
        if (t < FDIM) {
            float gi = gates[0 * 136 + t] + xv0[0];
            float gf = gates[1 * 136 + t] + xv0[1];
            float gg = gates[2 * 136 + t] + xv0[2];
            float go = gates[3 * 136 + t] + xv0[3];
            // rotate xg prefetch (3-deep) and issue next load early
            #pragma unroll
            for (int g = 0; g < 4; ++g) { xv0[g] = xv1[g]; xv1[g] = xv2[g]; }
            if (step + 3 < T) {
                #pragma unroll
                for (int g = 0; g < 4; ++g)
                    xv2[g] = xg[(size_t)(step + 3) * G4H + g * FDIM + t];
            }
            gi = 1.f / (1.f + __expf(-gi));
            gf = 1.f / (1.f + __expf(-gf));
            gg = 1.f - 2.f / (1.f + __expf(2.f * gg));
            go = 1.f / (1.f + __expf(-go));
            c = gf * c + gi * gg;
            float th = 1.f - 2.f / (1.f + __expf(2.f * c));
            float h = go * th;
            hs[(size_t)step * FDIM + t] = h;
            hl[t] = __float2half(h);
        }
        LDS_BARRIER();
    }
}

// ---------------------------------------------------------------------------
// out[M x 12] = hs[M x 128] @ w_fc^T + b_fc
// ---------------------------------------------------------------------------
__global__ __launch_bounds__(256) void fc_kernel(const float* __restrict__ hs,
                                                 const float* __restrict__ wfc,
                                                 const float* __restrict__ bfc,
                                                 float* __restrict__ out, int M) {
    __shared__ float wl[12 * FDIM];
    __shared__ float bl[12];
    const int tid = threadIdx.x;
    for (int i = tid; i < 12 * FDIM / 4; i += 256)
        ((float4*)wl)[i] = ((const float4*)wfc)[i];
    if (tid < 12) bl[tid] = bfc[tid];
    __syncthreads();

    int i = blockIdx.x * 256 + tid;
    if (i >= M) return;
    const float* hrow = hs + (size_t)i * FDIM;
    float acc[12];
    #pragma unroll
    for (int t = 0; t < 12; ++t) acc[t] = bl[t];
    for (int k = 0; k < FDIM; k += 4) {
        float4 h4 = *(const float4*)(hrow + k);
        #pragma unroll
        for (int t = 0; t < 12; ++t) {
            acc[t] += h4.x * wl[t * FDIM + k] + h4.y * wl[t * FDIM + k + 1]
                    + h4.z * wl[t * FDIM + k + 2] + h4.w * wl[t * FDIM + k + 3];
        }
    }
    #pragma unroll
    for (int t = 0; t < 12; ++t) out[(size_t)i * 12 + t] = acc[t];
}

// ---------------------------------------------------------------------------
extern "C" void kernel_launch(void* const* d_in, const int* in_sizes, int n_in,
                              void* d_out, int out_size, void* d_ws, size_t ws_size,
                              hipStream_t stream) {
    const float* x    = (const float*)d_in[0];
    const int*   ei   = (const int*)  d_in[1];
    const float* W1   = (const float*)d_in[2];
    const float* b1   = (const float*)d_in[3];
    const float* W2   = (const float*)d_in[4];
    const float* b2   = (const float*)d_in[5];
    const float* w_ih = (const float*)d_in[6];
    const float* w_hh = (const float*)d_in[7];
    const float* b_ih = (const float*)d_in[8];
    const float* b_hh = (const float*)d_in[9];
    const float* w_fc = (const float*)d_in[10];
    const float* b_fc = (const float*)d_in[11];

    const int N = in_sizes[0] / FDIM;     // 20000
    const int E = in_sizes[1] / 2;        // 1280000

    float* ws   = (float*)d_ws;
    int*   deg  = (int*)ws;               // [0, 20480) ints
    float* dinv = ws + 20480;
    float* whp  = ws + 40960;             // MFMA-packed fp16 w_hh: 32768 dwords
    float* hB   = ws + 40960 + 32768;     // h2: N*128
    float* big  = hB + (size_t)N * FDIM;  // xg region (N*512), aliases y/hA
    float* y    = big;                    // N*128 (dead before xg written)
    float* hA   = big + (size_t)N * FDIM; // h1   (dead before xg written)
    float* xg   = big;                    // N*512
    float* hs   = big + (size_t)N * G4H;  // N*128

    hipMemsetAsync(deg, 0, (size_t)N * sizeof(int), stream);
    deg_kernel<<<(E + 255) / 256, 256, 0, stream>>>(ei, deg, E);
    dinv_kernel<<<(N + 255) / 256, 256, 0, stream>>>(deg, dinv, N);
    pack_whh<<<(32768 + 255) / 256, 256, 0, stream>>>(w_hh, whp, 32768);

    const int gblocks = (N + 31) / 32;
    // layer 1
    gemm_nn<<<gblocks, 256, 0, stream>>>(x, W1, y, N);
    agg_init<<<(N * 32 + 255) / 256, 256, 0, stream>>>(y, dinv, b1, hA, N);
    agg_edges<<<(E * 32 + 255) / 256, 256, 0, stream>>>(y, ei, dinv, hA, E);
    relu_kernel<<<(N * 32 + 255) / 256, 256, 0, stream>>>(hA, N * 32);
    // layer 2
    gemm_nn<<<gblocks, 256, 0, stream>>>(hA, W2, y, N);
    agg_init<<<(N * 32 + 255) / 256, 256, 0, stream>>>(y, dinv, b2, hB, N);
    agg_edges<<<(E * 32 + 255) / 256, 256, 0, stream>>>(y, ei, dinv, hB, E);
    relu_kernel<<<(N * 32 + 255) / 256, 256, 0, stream>>>(hB, N * 32);
    // LSTM input projection
    gemm_nt_xg<<<dim3(gblocks, 4), 256, 0, stream>>>(hB, w_ih, b_ih, b_hh, xg, N);
    // sequential LSTM (single CU — the critical path)
    lstm_kernel<<<1, 512, 0, stream>>>(xg, whp, hs, N);
    // final projection
    fc_kernel<<<(N + 255) / 256, 256, 0, stream>>>(hs, w_fc, b_fc, (float*)d_out, N);
}

// Round 9
// 17487.645 us; speedup vs baseline: 1.4735x; 1.0794x over previous
//
#include <hip/hip_runtime.h>
#include <hip/hip_bf16.h>
#include <hip/hip_fp16.h>

// Problem constants (fixed by the reference)
#define FDIM 128      // F_IN == H == 128
#define G4H  512      // 4*H

typedef float f32x4 __attribute__((ext_vector_type(4)));
typedef _Float16 f16x8 __attribute__((ext_vector_type(8)));

union frag_cast { f32x4 f; f16x8 h; };

// LDS-only barrier: does NOT drain vmcnt (global ops stay in flight).
#define LDS_BARRIER() asm volatile("s_waitcnt lgkmcnt(0)\n\ts_barrier" ::: "memory")

#define AS1 __attribute__((address_space(1)))
#define AS3 __attribute__((address_space(3)))
// Async global->LDS, 16B/lane: LDS dst = uniform base + lane*16.
__device__ __forceinline__ void load_lds16(const float* g, float* l) {
    __builtin_amdgcn_global_load_lds((const AS1 unsigned int*)g,
                                     (AS3 unsigned int*)l, 16, 0, 0);
}

// ---------------------------------------------------------------------------
// degree / normalization
// ---------------------------------------------------------------------------
__global__ void deg_kernel(const int* __restrict__ ei, int* __restrict__ deg, int E) {
    int e = blockIdx.x * 256 + threadIdx.x;
    if (e < E) atomicAdd(&deg[ei[E + e]], 1);
}

__global__ void dinv_kernel(const int* __restrict__ deg, float* __restrict__ dinv, int N) {
    int n = blockIdx.x * 256 + threadIdx.x;
    if (n < N) dinv[n] = rsqrtf((float)(deg[n] + 1));   // +1 self-loop
}

// ---------------------------------------------------------------------------
// Prepack w_hh [512 x 128] fp32 into fp16 MFMA A-fragments.
// dword idx = (((w*4+rt)*4+kt)*64 + lane)*4 + d
//   lane: m = lane&15 (row in tile), q = lane>>4 (k-quad).
//   A[m][k]: lane holds halves k = 32kt + 8q + {2d, 2d+1}, row 64w+16rt+m.
// ---------------------------------------------------------------------------
__global__ void pack_whh(const float* __restrict__ whh, float* __restrict__ whp, int n) {
    int i = blockIdx.x * 256 + threadIdx.x;   // n = 32768 dwords
    if (i >= n) return;
    int d = i & 3, fi = i >> 2;
    int lane = fi & 63, kt = (fi >> 6) & 3, rt = (fi >> 8) & 3, w = fi >> 10;
    int m = lane & 15, q = lane >> 4;
    int r = 64 * w + 16 * rt + m;
    int k = 32 * kt + 8 * q + 2 * d;
    __half lo = __float2half(whh[r * FDIM + k]);
    __half hi = __float2half(whh[r * FDIM + k + 1]);
    unsigned u = ((unsigned)__half_as_ushort(hi) << 16) | (unsigned)__half_as_ushort(lo);
    whp[i] = __uint_as_float(u);
}

// ---------------------------------------------------------------------------
// C[M x 128] = A[M x 128] @ B[128 x 128]   (B is K-major: B[k*128 + j])
// ---------------------------------------------------------------------------
__global__ __launch_bounds__(256) void gemm_nn(const float* __restrict__ A,
                                               const float* __restrict__ B,
                                               float* __restrict__ C, int M) {
    __shared__ float Bl[64 * 132];
    __shared__ float Al[32][FDIM];
    const int tid = threadIdx.x;
    const int row0 = blockIdx.x * 32;

    for (int i = tid * 4; i < 32 * FDIM; i += 1024) {
        int r = i >> 7, k = i & 127;
        int row = row0 + r;
        float4 v = make_float4(0.f, 0.f, 0.f, 0.f);
        if (row < M) v = *(const float4*)(A + (size_t)row * FDIM + k);
        *(float4*)&Al[r][k] = v;
    }

    const int jg = tid & 31, rg = tid >> 5;
    float acc[4][4] = {};

    for (int kh = 0; kh < 2; ++kh) {
        __syncthreads();
        for (int i = tid * 4; i < 64 * FDIM; i += 1024) {
            int k = i >> 7, j = i & 127;
            *(float4*)&Bl[k * 132 + j] = *(const float4*)(B + (size_t)(kh * 64 + k) * FDIM + j);
        }
        __syncthreads();
        #pragma unroll 4
        for (int k = 0; k < 64; ++k) {
            float4 b4 = *(const float4*)&Bl[k * 132 + jg * 4];
            #pragma unroll
            for (int rr = 0; rr < 4; ++rr) {
                float a = Al[rg * 4 + rr][kh * 64 + k];
                acc[rr][0] += a * b4.x; acc[rr][1] += a * b4.y;
                acc[rr][2] += a * b4.z; acc[rr][3] += a * b4.w;
            }
        }
    }
    #pragma unroll
    for (int rr = 0; rr < 4; ++rr) {
        int row = row0 + rg * 4 + rr;
        if (row < M) {
            float4 v = make_float4(acc[rr][0], acc[rr][1], acc[rr][2], acc[rr][3]);
            *(float4*)(C + (size_t)row * FDIM + jg * 4) = v;
        }
    }
}

// ---------------------------------------------------------------------------
// xg[M x 512] = A[M x 128] @ B^T  (+ b_ih + b_hh), B is [512 x 128] row-major.
// ---------------------------------------------------------------------------
__global__ __launch_bounds__(256) void gemm_nt_xg(const float* __restrict__ A,
                                                  const float* __restrict__ B,
                                                  const float* __restrict__ bih,
                                                  const float* __restrict__ bhh,
                                                  float* __restrict__ C, int M) {
    __shared__ float Bl[64 * 132];
    __shared__ float Al[32][FDIM];
    const int tid = threadIdx.x;
    const int row0 = blockIdx.x * 32;
    const int chunk = blockIdx.y;

    for (int i = tid * 4; i < 32 * FDIM; i += 1024) {
        int r = i >> 7, k = i & 127;
        int row = row0 + r;
        float4 v = make_float4(0.f, 0.f, 0.f, 0.f);
        if (row < M) v = *(const float4*)(A + (size_t)row * FDIM + k);
        *(float4*)&Al[r][k] = v;
    }

    const int jg = tid & 31, rg = tid >> 5;
    float acc[4][4] = {};

    for (int kh = 0; kh < 2; ++kh) {
        __syncthreads();
        for (int i = tid * 4; i < 128 * 64; i += 1024) {
            int g = i >> 6, kl = i & 63;
            float4 v = *(const float4*)(B + (size_t)(chunk * 128 + g) * FDIM + kh * 64 + kl);
            Bl[(kl + 0) * 132 + g] = v.x;
            Bl[(kl + 1) * 132 + g] = v.y;
            Bl[(kl + 2) * 132 + g] = v.z;
            Bl[(kl + 3) * 132 + g] = v.w;
        }
        __syncthreads();
        #pragma unroll 4
        for (int k = 0; k < 64; ++k) {
            float4 b4 = *(const float4*)&Bl[k * 132 + jg * 4];
            #pragma unroll
            for (int rr = 0; rr < 4; ++rr) {
                float a = Al[rg * 4 + rr][kh * 64 + k];
                acc[rr][0] += a * b4.x; acc[rr][1] += a * b4.y;
                acc[rr][2] += a * b4.z; acc[rr][3] += a * b4.w;
            }
        }
    }
    const int col0 = chunk * 128 + jg * 4;
    float4 bsum = make_float4(bih[col0 + 0] + bhh[col0 + 0],
                              bih[col0 + 1] + bhh[col0 + 1],
                              bih[col0 + 2] + bhh[col0 + 2],
                              bih[col0 + 3] + bhh[col0 + 3]);
    #pragma unroll
    for (int rr = 0; rr < 4; ++rr) {
        int row = row0 + rg * 4 + rr;
        if (row < M) {
            float4 v = make_float4(acc[rr][0] + bsum.x, acc[rr][1] + bsum.y,
                                   acc[rr][2] + bsum.z, acc[rr][3] + bsum.w);
            *(float4*)(C + (size_t)row * G4H + col0) = v;
        }
    }
}

// ---------------------------------------------------------------------------
// GCN aggregation
// ---------------------------------------------------------------------------
__global__ void agg_init(const float* __restrict__ y, const float* __restrict__ dinv,
                         const float* __restrict__ bias, float* __restrict__ o, int N) {
    int idx = blockIdx.x * 256 + threadIdx.x;
    int n = idx >> 5, cc = (idx & 31) * 4;
    if (n >= N) return;
    float s = dinv[n]; s = s * s;
    float4 v = *(const float4*)(y + (size_t)n * FDIM + cc);
    float4 b = *(const float4*)(bias + cc);
    float4 r = make_float4(v.x * s + b.x, v.y * s + b.y, v.z * s + b.z, v.w * s + b.w);
    *(float4*)(o + (size_t)n * FDIM + cc) = r;
}

__global__ void agg_edges(const float* __restrict__ y, const int* __restrict__ ei,
                          const float* __restrict__ dinv, float* __restrict__ o, int E) {
    int idx = blockIdx.x * 256 + threadIdx.x;
    int e = idx >> 5, cc = (idx & 31) * 4;
    if (e >= E) return;
    int s = ei[e], d = ei[E + e];
    float nrm = dinv[s] * dinv[d];
    float4 v = *(const float4*)(y + (size_t)s * FDIM + cc);
    float* dst = o + (size_t)d * FDIM + cc;
    atomicAdd(dst + 0, v.x * nrm);
    atomicAdd(dst + 1, v.y * nrm);
    atomicAdd(dst + 2, v.z * nrm);
    atomicAdd(dst + 3, v.w * nrm);
}

__global__ void relu_kernel(float* __restrict__ x, int n4) {
    int i = blockIdx.x * 256 + threadIdx.x;
    if (i < n4) {
        float4 v = ((float4*)x)[i];
        v.x = fmaxf(v.x, 0.f); v.y = fmaxf(v.y, 0.f);
        v.z = fmaxf(v.z, 0.f); v.w = fmaxf(v.w, 0.f);
        ((float4*)x)[i] = v;
    }
}

// ---------------------------------------------------------------------------
// LSTM v9 = v8 (MFMA GEMV, AGPR weights, LDS-only barriers) + vm-free
// consumer waves. v8's residual 1742 cyc/step: phase-B waves still issued
// global xg loads with a loop-variant conditional -> compiler emitted a
// conservative vmcnt wait before every xv use (~800-1000 cyc HBM wait/step).
// Now: wave 2 streams xg into a 4-slot LDS ring via global_load_lds
// (distance 3, explicit s_waitcnt vmcnt(6) = the ONLY vm wait in the loop,
// ~2000 cyc of slack vs ~900 cyc HBM latency). Phase B reads xg from LDS;
// its only vm op is the hs store, which nothing waits on.
// ---------------------------------------------------------------------------
__global__ void __launch_bounds__(512, 2)
lstm_kernel(const float* __restrict__ xg, const float* __restrict__ whp,
            float* __restrict__ hs, int T) {
    __shared__ __align__(16) __half hl[FDIM];
    __shared__ __align__(16) float gates[4 * 136];   // stride 136 floats per gate
    __shared__ __align__(16) float xr[4][G4H];       // xg ring, slot = step & 3
    const int t = threadIdx.x;
    const int w = t >> 6;          // wave 0..7
    const int lane = t & 63;
    const int q = lane >> 4;       // k-quad / C row-quad
    const int n = lane & 15;       // C column

    // Load + pin A-fragments into AGPRs: aw[rt][kt], 4 dwords (8 fp16) each.
    f16x8 aw[4][4];
    {
        const f32x4* wp4 = (const f32x4*)whp;
        #pragma unroll
        for (int rt = 0; rt < 4; ++rt) {
            #pragma unroll
            for (int kt = 0; kt < 4; ++kt) {
                frag_cast fc;
                fc.f = wp4[((w * 4 + rt) * 4 + kt) * 64 + lane];
                f16x8 tmp = fc.h;
                asm volatile("" : "=a"(aw[rt][kt]) : "0"(tmp));  // pin to AGPR class
            }
        }
    }

    float c = 0.f;
    if (t < FDIM) hl[t] = __float2half(0.f);
    // Prime the xg ring: slots 0..2 (6 outstanding vm ops on wave 2).
    if (w == 2) {
        #pragma unroll
        for (int i = 0; i < 3; ++i) {
            const float* g0 = xg + (size_t)i * G4H + lane * 4;
            load_lds16(g0,       &xr[i][0]);
            load_lds16(g0 + 256, &xr[i][256]);
        }
    }
    __syncthreads();   // pre-loop: full barrier is fine (vm ops above have slack)

    const int gsel = w >> 1;                      // this wave's gate
    const int j0 = (w & 1) * 64 + 16 * n + 4 * q; // writeout j (lanes n<4)

    for (int step = 0; step < T; ++step) {
        // ---- phase A: MFMA GEMV, all 8 waves ----
        f32x4 cd0 = {0.f, 0.f, 0.f, 0.f}, cd1 = cd0, cd2 = cd0, cd3 = cd0;
        #pragma unroll
        for (int kt = 0; kt < 4; ++kt) {
            // B-frag: h[32kt + 8q .. +8) broadcast to all 16 columns.
            frag_cast bc;
            bc.f = *(const f32x4*)((const char*)hl + kt * 64 + q * 16);
            f16x8 b = bc.h;
            cd0 = __builtin_amdgcn_mfma_f32_16x16x32_f16(aw[0][kt], b, cd0, 0, 0, 0);
            cd1 = __builtin_amdgcn_mfma_f32_16x16x32_f16(aw[1][kt], b, cd1, 0, 0, 0);
            cd2 = __builtin_amdgcn_mfma_f32_16x16x32_f16(aw[2][kt], b, cd2, 0, 0, 0);
            cd3 = __builtin_amdgcn_mfma_f32_16x16x32_f16(aw[3][kt], b, cd3, 0, 0, 0);
        }
        // Every C column holds the same values; lanes n<4 write row-tile rt=n.
        f32x4 sel = (n == 0) ? cd0 : (n == 1) ? cd1 : (n == 2) ? cd2 : cd3;
        if (n < 4)
            *(f32x4*)&gates[gsel * 136 + j0] = sel;

        // ---- wave 2: stream xg[step+3] into ring slot (step+3)&3 ----
        if (w == 2) {
            int idx = step + 3; if (idx >= T) idx = T - 1;
            const float* g0 = xg + (size_t)idx * G4H + lane * 4;
            load_lds16(g0,       &xr[idx & 3][0]);
            load_lds16(g0 + 256, &xr[idx & 3][256]);
            // guarantee slot step&3 (issued 3 steps ago) has landed
            asm volatile("s_waitcnt vmcnt(6)" ::: "memory");
        }
        LDS_BARRIER();

        // ---- phase B: 2 waves, thread j: combine + activations + state ----
        if (t < FDIM) {
            const float* xs = xr[step & 3];
            float gi = gates[0 * 136 + t] + xs[0 * FDIM + t];
            float gf = gates[1 * 136 + t] + xs[1 * FDIM + t];
            float gg = gates[2 * 136 + t] + xs[2 * FDIM + t];
            float go = gates[3 * 136 + t] + xs[3 * FDIM + t];
            gi = 1.f / (1.f + __expf(-gi));
            gf = 1.f / (1.f + __expf(-gf));
            gg = 1.f - 2.f / (1.f + __expf(2.f * gg));
            go = 1.f / (1.f + __expf(-go));
            c = gf * c + gi * gg;
            float th = 1.f - 2.f / (1.f + __expf(2.f * c));
            float h = go * th;
            hs[(size_t)step * FDIM + t] = h;   // store: never waited on in-loop
            hl[t] = __float2half(h);
        }
        LDS_BARRIER();
    }
}

// ---------------------------------------------------------------------------
// out[M x 12] = hs[M x 128] @ w_fc^T + b_fc
// ---------------------------------------------------------------------------
__global__ __launch_bounds__(256) void fc_kernel(const float* __restrict__ hs,
                                                 const float* __restrict__ wfc,
                                                 const float* __restrict__ bfc,
                                                 float* __restrict__ out, int M) {
    __shared__ float wl[12 * FDIM];
    __shared__ float bl[12];
    const int tid = threadIdx.x;
    for (int i = tid; i < 12 * FDIM / 4; i += 256)
        ((float4*)wl)[i] = ((const float4*)wfc)[i];
    if (tid < 12) bl[tid] = bfc[tid];
    __syncthreads();

    int i = blockIdx.x * 256 + tid;
    if (i >= M) return;
    const float* hrow = hs + (size_t)i * FDIM;
    float acc[12];
    #pragma unroll
    for (int t = 0; t < 12; ++t) acc[t] = bl[t];
    for (int k = 0; k < FDIM; k += 4) {
        float4 h4 = *(const float4*)(hrow + k);
        #pragma unroll
        for (int t = 0; t < 12; ++t) {
            acc[t] += h4.x * wl[t * FDIM + k] + h4.y * wl[t * FDIM + k + 1]
                    + h4.z * wl[t * FDIM + k + 2] + h4.w * wl[t * FDIM + k + 3];
        }
    }
    #pragma unroll
    for (int t = 0; t < 12; ++t) out[(size_t)i * 12 + t] = acc[t];
}

// ---------------------------------------------------------------------------
extern "C" void kernel_launch(void* const* d_in, const int* in_sizes, int n_in,
                              void* d_out, int out_size, void* d_ws, size_t ws_size,
                              hipStream_t stream) {
    const float* x    = (const float*)d_in[0];
    const int*   ei   = (const int*)  d_in[1];
    const float* W1   = (const float*)d_in[2];
    const float* b1   = (const float*)d_in[3];
    const float* W2   = (const float*)d_in[4];
    const float* b2   = (const float*)d_in[5];
    const float* w_ih = (const float*)d_in[6];
    const float* w_hh = (const float*)d_in[7];
    const float* b_ih = (const float*)d_in[8];
    const float* b_hh = (const float*)d_in[9];
    const float* w_fc = (const float*)d_in[10];
    const float* b_fc = (const float*)d_in[11];

    const int N = in_sizes[0] / FDIM;     // 20000
    const int E = in_sizes[1] / 2;        // 1280000

    float* ws   = (float*)d_ws;
    int*   deg  = (int*)ws;               // [0, 20480) ints
    float* dinv = ws + 20480;
    float* whp  = ws + 40960;             // MFMA-packed fp16 w_hh: 32768 dwords
    float* hB   = ws + 40960 + 32768;     // h2: N*128
    float* big  = hB + (size_t)N * FDIM;  // xg region (N*512), aliases y/hA
    float* y    = big;                    // N*128 (dead before xg written)
    float* hA   = big + (size_t)N * FDIM; // h1   (dead before xg written)
    float* xg   = big;                    // N*512
    float* hs   = big + (size_t)N * G4H;  // N*128

    hipMemsetAsync(deg, 0, (size_t)N * sizeof(int), stream);
    deg_kernel<<<(E + 255) / 256, 256, 0, stream>>>(ei, deg, E);
    dinv_kernel<<<(N + 255) / 256, 256, 0, stream>>>(deg, dinv, N);
    pack_whh<<<(32768 + 255) / 256, 256, 0, stream>>>(w_hh, whp, 32768);

    const int gblocks = (N + 31) / 32;
    // layer 1
    gemm_nn<<<gblocks, 256, 0, stream>>>(x, W1, y, N);
    agg_init<<<(N * 32 + 255) / 256, 256, 0, stream>>>(y, dinv, b1, hA, N);
    agg_edges<<<(E * 32 + 255) / 256, 256, 0, stream>>>(y, ei, dinv, hA, E);
    relu_kernel<<<(N * 32 + 255) / 256, 256, 0, stream>>>(hA, N * 32);
    // layer 2
    gemm_nn<<<gblocks, 256, 0, stream>>>(hA, W2, y, N);
    agg_init<<<(N * 32 + 255) / 256, 256, 0, stream>>>(y, dinv, b2, hB, N);
    agg_edges<<<(E * 32 + 255) / 256, 256, 0, stream>>>(y, ei, dinv, hB, E);
    relu_kernel<<<(N * 32 + 255) / 256, 256, 0, stream>>>(hB, N * 32);
    // LSTM input projection
    gemm_nt_xg<<<dim3(gblocks, 4), 256, 0, stream>>>(hB, w_ih, b_ih, b_hh, xg, N);
    // sequential LSTM (single CU — the critical path)
    lstm_kernel<<<1, 512, 0, stream>>>(xg, whp, hs, N);
    // final projection
    fc_kernel<<<(N + 255) / 256, 256, 0, stream>>>(hs, w_fc, b_fc, (float*)d_out, N);
}

// Round 10
// 15367.827 us; speedup vs baseline: 1.6767x; 1.1379x over previous
//
#include <hip/hip_runtime.h>
#include <hip/hip_bf16.h>
#include <hip/hip_fp16.h>

// Problem constants (fixed by the reference)
#define FDIM 128      // F_IN == H == 128
#define G4H  512      // 4*H

typedef float f32x4 __attribute__((ext_vector_type(4)));
typedef _Float16 f16x8 __attribute__((ext_vector_type(8)));

union frag_cast { f32x4 f; f16x8 h; };

// LDS-only barrier: does NOT drain vmcnt (global ops stay in flight).
#define LDS_BARRIER() asm volatile("s_waitcnt lgkmcnt(0)\n\ts_barrier" ::: "memory")

#define AS1 __attribute__((address_space(1)))
#define AS3 __attribute__((address_space(3)))
// Async global->LDS, 16B/lane: LDS dst = uniform base + lane*16.
__device__ __forceinline__ void load_lds16(const float* g, float* l) {
    __builtin_amdgcn_global_load_lds((const AS1 unsigned int*)g,
                                     (AS3 unsigned int*)l, 16, 0, 0);
}

// ---------------------------------------------------------------------------
// degree / normalization
// ---------------------------------------------------------------------------
__global__ void deg_kernel(const int* __restrict__ ei, int* __restrict__ deg, int E) {
    int e = blockIdx.x * 256 + threadIdx.x;
    if (e < E) atomicAdd(&deg[ei[E + e]], 1);
}

__global__ void dinv_kernel(const int* __restrict__ deg, float* __restrict__ dinv, int N) {
    int n = blockIdx.x * 256 + threadIdx.x;
    if (n < N) dinv[n] = rsqrtf((float)(deg[n] + 1));   // +1 self-loop
}

// ---------------------------------------------------------------------------
// CSR build: exclusive scan of deg (1024 thr x 20 nodes), then edge scatter.
// ---------------------------------------------------------------------------
__global__ __launch_bounds__(1024) void scan_kernel(const int* __restrict__ deg,
                                                    int* __restrict__ rs,
                                                    int* __restrict__ cursor,
                                                    int N, int E) {
    __shared__ int buf[2][1024];
    const int t = threadIdx.x;
    const int base = t * 20;
    int loc[20]; int s = 0;
    #pragma unroll
    for (int i = 0; i < 20; ++i) {
        int n = base + i;
        int d = (n < N) ? deg[n] : 0;
        loc[i] = s; s += d;
    }
    buf[0][t] = s; __syncthreads();
    int pb = 0;
    for (int off = 1; off < 1024; off <<= 1) {
        int v = buf[pb][t] + ((t >= off) ? buf[pb][t - off] : 0);
        buf[pb ^ 1][t] = v; pb ^= 1; __syncthreads();
    }
    int pre = (t > 0) ? buf[pb][t - 1] : 0;   // exclusive prefix
    #pragma unroll
    for (int i = 0; i < 20; ++i) {
        int n = base + i;
        if (n < N) { int v = pre + loc[i]; rs[n] = v; cursor[n] = v; }
    }
    if (t == 0) rs[N] = E;
}

__global__ void scatter_kernel(const int* __restrict__ ei, int* __restrict__ cursor,
                               int* __restrict__ csr_src, int E) {
    int e = blockIdx.x * 256 + threadIdx.x;
    if (e >= E) return;
    int s = ei[e], d = ei[E + e];
    int pos = atomicAdd(&cursor[d], 1);
    csr_src[pos] = s;
}

// ---------------------------------------------------------------------------
// C[M x 128] = A[M x 128] @ B[128 x 128]   (B is K-major: B[k*128 + j])
// ---------------------------------------------------------------------------
__global__ __launch_bounds__(256) void gemm_nn(const float* __restrict__ A,
                                               const float* __restrict__ B,
                                               float* __restrict__ C, int M) {
    __shared__ float Bl[64 * 132];
    __shared__ float Al[32][FDIM];
    const int tid = threadIdx.x;
    const int row0 = blockIdx.x * 32;

    for (int i = tid * 4; i < 32 * FDIM; i += 1024) {
        int r = i >> 7, k = i & 127;
        int row = row0 + r;
        float4 v = make_float4(0.f, 0.f, 0.f, 0.f);
        if (row < M) v = *(const float4*)(A + (size_t)row * FDIM + k);
        *(float4*)&Al[r][k] = v;
    }

    const int jg = tid & 31, rg = tid >> 5;
    float acc[4][4] = {};

    for (int kh = 0; kh < 2; ++kh) {
        __syncthreads();
        for (int i = tid * 4; i < 64 * FDIM; i += 1024) {
            int k = i >> 7, j = i & 127;
            *(float4*)&Bl[k * 132 + j] = *(const float4*)(B + (size_t)(kh * 64 + k) * FDIM + j);
        }
        __syncthreads();
        #pragma unroll 4
        for (int k = 0; k < 64; ++k) {
            float4 b4 = *(const float4*)&Bl[k * 132 + jg * 4];
            #pragma unroll
            for (int rr = 0; rr < 4; ++rr) {
                float a = Al[rg * 4 + rr][kh * 64 + k];
                acc[rr][0] += a * b4.x; acc[rr][1] += a * b4.y;
                acc[rr][2] += a * b4.z; acc[rr][3] += a * b4.w;
            }
        }
    }
    #pragma unroll
    for (int rr = 0; rr < 4; ++rr) {
        int row = row0 + rg * 4 + rr;
        if (row < M) {
            float4 v = make_float4(acc[rr][0], acc[rr][1], acc[rr][2], acc[rr][3]);
            *(float4*)(C + (size_t)row * FDIM + jg * 4) = v;
        }
    }
}

// ---------------------------------------------------------------------------
// xg[M x 512] = A[M x 128] @ B^T  (+ b_ih + b_hh), B is [512 x 128] row-major.
// ---------------------------------------------------------------------------
__global__ __launch_bounds__(256) void gemm_nt_xg(const float* __restrict__ A,
                                                  const float* __restrict__ B,
                                                  const float* __restrict__ bih,
                                                  const float* __restrict__ bhh,
                                                  float* __restrict__ C, int M) {
    __shared__ float Bl[64 * 132];
    __shared__ float Al[32][FDIM];
    const int tid = threadIdx.x;
    const int row0 = blockIdx.x * 32;
    const int chunk = blockIdx.y;

    for (int i = tid * 4; i < 32 * FDIM; i += 1024) {
        int r = i >> 7, k = i & 127;
        int row = row0 + r;
        float4 v = make_float4(0.f, 0.f, 0.f, 0.f);
        if (row < M) v = *(const float4*)(A + (size_t)row * FDIM + k);
        *(float4*)&Al[r][k] = v;
    }

    const int jg = tid & 31, rg = tid >> 5;
    float acc[4][4] = {};

    for (int kh = 0; kh < 2; ++kh) {
        __syncthreads();
        for (int i = tid * 4; i < 128 * 64; i += 1024) {
            int g = i >> 6, kl = i & 63;
            float4 v = *(const float4*)(B + (size_t)(chunk * 128 + g) * FDIM + kh * 64 + kl);
            Bl[(kl + 0) * 132 + g] = v.x;
            Bl[(kl + 1) * 132 + g] = v.y;
            Bl[(kl + 2) * 132 + g] = v.z;
            Bl[(kl + 3) * 132 + g] = v.w;
        }
        __syncthreads();
        #pragma unroll 4
        for (int k = 0; k < 64; ++k) {
            float4 b4 = *(const float4*)&Bl[k * 132 + jg * 4];
            #pragma unroll
            for (int rr = 0; rr < 4; ++rr) {
                float a = Al[rg * 4 + rr][kh * 64 + k];
                acc[rr][0] += a * b4.x; acc[rr][1] += a * b4.y;
                acc[rr][2] += a * b4.z; acc[rr][3] += a * b4.w;
            }
        }
    }
    const int col0 = chunk * 128 + jg * 4;
    float4 bsum = make_float4(bih[col0 + 0] + bhh[col0 + 0],
                              bih[col0 + 1] + bhh[col0 + 1],
                              bih[col0 + 2] + bhh[col0 + 2],
                              bih[col0 + 3] + bhh[col0 + 3]);
    #pragma unroll
    for (int rr = 0; rr < 4; ++rr) {
        int row = row0 + rg * 4 + rr;
        if (row < M) {
            float4 v = make_float4(acc[rr][0] + bsum.x, acc[rr][1] + bsum.y,
                                   acc[rr][2] + bsum.z, acc[rr][3] + bsum.w);
            *(float4*)(C + (size_t)row * G4H + col0) = v;
        }
    }
}

// ---------------------------------------------------------------------------
// Fused GCN aggregation (CSR gather): one wave per node, accumulate in
// registers (float2/lane), single plain write. Replaces atomic scatter
// (2.56 GB RMW write traffic) + agg_init + relu.
//   o[n] = relu( y[n]*dinv[n]^2 + sum_{s->n} y[s]*dinv[s]*dinv[n] + bias )
// ---------------------------------------------------------------------------
__global__ __launch_bounds__(256) void agg_gather(const float* __restrict__ y,
                                                  const int* __restrict__ rs,
                                                  const int* __restrict__ csr_src,
                                                  const float* __restrict__ dinv,
                                                  const float* __restrict__ bias,
                                                  float* __restrict__ o, int N) {
    const int node = blockIdx.x * 4 + (threadIdx.x >> 6);
    if (node >= N) return;
    const int lane = threadIdx.x & 63;
    const int beg = rs[node], end = rs[node + 1];
    const float dn = dinv[node];

    float2 yv = *(const float2*)(y + (size_t)node * FDIM + lane * 2);
    float2 acc = make_float2(yv.x * dn * dn, yv.y * dn * dn);

    for (int base = beg; base < end; base += 64) {
        int cnt = end - base; if (cnt > 64) cnt = 64;
        int msrc = 0; float mnrm = 0.f;
        if (lane < cnt) {
            msrc = csr_src[base + lane];
            mnrm = dinv[msrc] * dn;
        }
        for (int j = 0; j < cnt; ++j) {
            int s = __shfl(msrc, j);
            float nr = __shfl(mnrm, j);
            float2 v = *(const float2*)(y + (size_t)s * FDIM + lane * 2);
            acc.x += v.x * nr;
            acc.y += v.y * nr;
        }
    }
    float2 b = *(const float2*)(bias + lane * 2);
    acc.x = fmaxf(acc.x + b.x, 0.f);
    acc.y = fmaxf(acc.y + b.y, 0.f);
    *(float2*)(o + (size_t)node * FDIM + lane * 2) = acc;
}

// ---------------------------------------------------------------------------
// Prepack w_hh [512 x 128] fp32 into fp16 MFMA A-fragments (4-wave layout).
// dword idx = (((w*8+rt)*4+kt)*64 + lane)*4 + d
//   wave w (0..3) = gate w; row-tile rt (0..7): rows 128w+16rt+m;
//   lane: m = lane&15, q = lane>>4; k = 32kt + 8q + {2d,2d+1}.
// ---------------------------------------------------------------------------
__global__ void pack_whh(const float* __restrict__ whh, float* __restrict__ whp, int n) {
    int i = blockIdx.x * 256 + threadIdx.x;   // n = 32768 dwords
    if (i >= n) return;
    int d = i & 3, fi = i >> 2;
    int lane = fi & 63, kt = (fi >> 6) & 3, rt = (fi >> 8) & 7, w = fi >> 11;
    int m = lane & 15, q = lane >> 4;
    int r = 128 * w + 16 * rt + m;
    int k = 32 * kt + 8 * q + 2 * d;
    __half lo = __float2half(whh[r * FDIM + k]);
    __half hi = __float2half(whh[r * FDIM + k + 1]);
    unsigned u = ((unsigned)__half_as_ushort(hi) << 16) | (unsigned)__half_as_ushort(lo);
    whp[i] = __uint_as_float(u);
}

// ---------------------------------------------------------------------------
// LSTM v10 = v9 structure with 4 waves instead of 8. v9's residual 1587
// cyc/step exceeded the ~620-cyc dependence-chain model; the excess scales
// with wave count: DS-pipe serialization (8 waves x 4 ds_read_b128 + 8
// ds_write_b128 = ~480 cyc/step) + 8-wave barrier skew. Now: wave w = gate w,
// 8 row-tiles x 4 K-tiles = 32 MFMA/wave, 128 AGPRs/thread ("=a" pin, proven
// v7-v9). DS traffic halves (16 reads + 4 writes); barriers span 4 waves.
// Phase B (waves 0-1) and the wave-2 xg LDS ring are unchanged from v9.
// ---------------------------------------------------------------------------
__global__ void __launch_bounds__(256)
lstm_kernel(const float* __restrict__ xg, const float* __restrict__ whp,
            float* __restrict__ hs, int T) {
    __shared__ __align__(16) __half hl[FDIM];
    __shared__ __align__(16) float gates[4 * 136];   // stride 136 floats per gate
    __shared__ __align__(16) float xr[4][G4H];       // xg ring, slot = step & 3
    const int t = threadIdx.x;
    const int w = t >> 6;          // wave 0..3 = gate w
    const int lane = t & 63;
    const int q = lane >> 4;       // k-quad / C row-quad
    const int n = lane & 15;       // C column

    // Load + pin A-fragments into AGPRs: aw[rt][kt], 8 tiles x 4 kt.
    f16x8 aw[8][4];
    {
        const f32x4* wp4 = (const f32x4*)whp;
        #pragma unroll
        for (int rt = 0; rt < 8; ++rt) {
            #pragma unroll
            for (int kt = 0; kt < 4; ++kt) {
                frag_cast fc;
                fc.f = wp4[((w * 8 + rt) * 4 + kt) * 64 + lane];
                f16x8 tmp = fc.h;
                asm volatile("" : "=a"(aw[rt][kt]) : "0"(tmp));  // pin to AGPR class
            }
        }
    }

    float c = 0.f;
    if (t < FDIM) hl[t] = __float2half(0.f);
    // Prime the xg ring: slots 0..2 (6 outstanding vm ops on wave 2).
    if (w == 2) {
        #pragma unroll
        for (int i = 0; i < 3; ++i) {
            const float* g0 = xg + (size_t)i * G4H + lane * 4;
            load_lds16(g0,       &xr[i][0]);
            load_lds16(g0 + 256, &xr[i][256]);
        }
    }
    __syncthreads();   // pre-loop full barrier (vm ops above have slack)

    const int j0 = 16 * n + 4 * q;  // writeout j for lanes n<8 (tile rt=n)

    for (int step = 0; step < T; ++step) {
        // ---- phase A: MFMA GEMV, all 4 waves ----
        f32x4 cd[8];
        #pragma unroll
        for (int rt = 0; rt < 8; ++rt) cd[rt] = f32x4{0.f, 0.f, 0.f, 0.f};
        #pragma unroll
        for (int kt = 0; kt < 4; ++kt) {
            // B-frag: h[32kt + 8q .. +8) broadcast to all 16 columns.
            frag_cast bc;
            bc.f = *(const f32x4*)((const char*)hl + kt * 64 + q * 16);
            f16x8 b = bc.h;
            #pragma unroll
            for (int rt = 0; rt < 8; ++rt)
                cd[rt] = __builtin_amdgcn_mfma_f32_16x16x32_f16(aw[rt][kt], b, cd[rt], 0, 0, 0);
        }
        // Every C column holds the same values; lanes n<8 write tile rt=n.
        {
            int nl = n & 3;
            f32x4 selA = (nl == 0) ? cd[0] : (nl == 1) ? cd[1] : (nl == 2) ? cd[2] : cd[3];
            f32x4 selB = (nl == 0) ? cd[4] : (nl == 1) ? cd[5] : (nl == 2) ? cd[6] : cd[7];
            f32x4 sel = (n < 4) ? selA : selB;
            if (n < 8)
                *(f32x4*)&gates[w * 136 + j0] = sel;
        }

        // ---- wave 2: stream xg[step+3] into ring slot (step+3)&3 ----
        if (w == 2) {
            int idx = step + 3; if (idx >= T) idx = T - 1;
            const float* g0 = xg + (size_t)idx * G4H + lane * 4;
            load_lds16(g0,       &xr[idx & 3][0]);
            load_lds16(g0 + 256, &xr[idx & 3][256]);
            // guarantee slot step&3 (issued 3 steps ago) has landed
            asm volatile("s_waitcnt vmcnt(6)" ::: "memory");
        }
        LDS_BARRIER();

        // ---- phase B: 2 waves, thread j: combine + activations + state ----
        if (t < FDIM) {
            const float* xs = xr[step & 3];
            float gi = gates[0 * 136 + t] + xs[0 * FDIM + t];
            float gf = gates[1 * 136 + t] + xs[1 * FDIM + t];
            float gg = gates[2 * 136 + t] + xs[2 * FDIM + t];
            float go = gates[3 * 136 + t] + xs[3 * FDIM + t];
            gi = 1.f / (1.f + __expf(-gi));
            gf = 1.f / (1.f + __expf(-gf));
            gg = 1.f - 2.f / (1.f + __expf(2.f * gg));
            go = 1.f / (1.f + __expf(-go));
            c = gf * c + gi * gg;
            float th = 1.f - 2.f / (1.f + __expf(2.f * c));
            float h = go * th;
            hs[(size_t)step * FDIM + t] = h;   // store: never waited on in-loop
            hl[t] = __float2half(h);
        }
        LDS_BARRIER();
    }
}

// ---------------------------------------------------------------------------
// out[M x 12] = hs[M x 128] @ w_fc^T + b_fc
// ---------------------------------------------------------------------------
__global__ __launch_bounds__(256) void fc_kernel(const float* __restrict__ hs,
                                                 const float* __restrict__ wfc,
                                                 const float* __restrict__ bfc,
                                                 float* __restrict__ out, int M) {
    __shared__ float wl[12 * FDIM];
    __shared__ float bl[12];
    const int tid = threadIdx.x;
    for (int i = tid; i < 12 * FDIM / 4; i += 256)
        ((float4*)wl)[i] = ((const float4*)wfc)[i];
    if (tid < 12) bl[tid] = bfc[tid];
    __syncthreads();

    int i = blockIdx.x * 256 + tid;
    if (i >= M) return;
    const float* hrow = hs + (size_t)i * FDIM;
    float acc[12];
    #pragma unroll
    for (int t = 0; t < 12; ++t) acc[t] = bl[t];
    for (int k = 0; k < FDIM; k += 4) {
        float4 h4 = *(const float4*)(hrow + k);
        #pragma unroll
        for (int t = 0; t < 12; ++t) {
            acc[t] += h4.x * wl[t * FDIM + k] + h4.y * wl[t * FDIM + k + 1]
                    + h4.z * wl[t * FDIM + k + 2] + h4.w * wl[t * FDIM + k + 3];
        }
    }
    #pragma unroll
    for (int t = 0; t < 12; ++t) out[(size_t)i * 12 + t] = acc[t];
}

// ---------------------------------------------------------------------------
extern "C" void kernel_launch(void* const* d_in, const int* in_sizes, int n_in,
                              void* d_out, int out_size, void* d_ws, size_t ws_size,
                              hipStream_t stream) {
    const float* x    = (const float*)d_in[0];
    const int*   ei   = (const int*)  d_in[1];
    const float* W1   = (const float*)d_in[2];
    const float* b1   = (const float*)d_in[3];
    const float* W2   = (const float*)d_in[4];
    const float* b2   = (const float*)d_in[5];
    const float* w_ih = (const float*)d_in[6];
    const float* w_hh = (const float*)d_in[7];
    const float* b_ih = (const float*)d_in[8];
    const float* b_hh = (const float*)d_in[9];
    const float* w_fc = (const float*)d_in[10];
    const float* b_fc = (const float*)d_in[11];

    const int N = in_sizes[0] / FDIM;     // 20000
    const int E = in_sizes[1] / 2;        // 1280000

    float* ws   = (float*)d_ws;
    int*   deg  = (int*)ws;                       // 20480 ints
    float* dinv = ws + 20480;                     // 20480 floats
    float* whp  = ws + 40960;                     // 32768 dwords (packed fragments)
    int*   rs   = (int*)(ws + 73728);             // 20992 ints (N+1 used)
    int*   cur  = (int*)(ws + 94720);             // 20480 ints
    int*   csr  = (int*)(ws + 115200);            // E ints
    float* hB   = ws + 115200 + 1280000;          // N*128
    float* big  = hB + (size_t)N * FDIM;          // xg region (N*512), aliases y/hA
    float* y    = big;                            // N*128 (dead before xg written)
    float* hA   = big + (size_t)N * FDIM;         // h1   (dead before xg written)
    float* xg   = big;                            // N*512
    float* hs   = big + (size_t)N * G4H;          // N*128

    hipMemsetAsync(deg, 0, (size_t)N * sizeof(int), stream);
    deg_kernel<<<(E + 255) / 256, 256, 0, stream>>>(ei, deg, E);
    dinv_kernel<<<(N + 255) / 256, 256, 0, stream>>>(deg, dinv, N);
    scan_kernel<<<1, 1024, 0, stream>>>(deg, rs, cur, N, E);
    scatter_kernel<<<(E + 255) / 256, 256, 0, stream>>>(ei, cur, csr, E);
    pack_whh<<<(32768 + 255) / 256, 256, 0, stream>>>(w_hh, whp, 32768);

    const int gblocks = (N + 31) / 32;
    const int ablocks = (N + 3) / 4;
    // layer 1
    gemm_nn<<<gblocks, 256, 0, stream>>>(x, W1, y, N);
    agg_gather<<<ablocks, 256, 0, stream>>>(y, rs, csr, dinv, b1, hA, N);
    // layer 2
    gemm_nn<<<gblocks, 256, 0, stream>>>(hA, W2, y, N);
    agg_gather<<<ablocks, 256, 0, stream>>>(y, rs, csr, dinv, b2, hB, N);
    // LSTM input projection
    gemm_nt_xg<<<dim3(gblocks, 4), 256, 0, stream>>>(hB, w_ih, b_ih, b_hh, xg, N);
    // sequential LSTM (single CU — the critical path)
    lstm_kernel<<<1, 256, 0, stream>>>(xg, whp, hs, N);
    // final projection
    fc_kernel<<<(N + 255) / 256, 256, 0, stream>>>(hs, w_fc, b_fc, (float*)d_out, N);
}